// Round 1
// baseline (1161.978 us; speedup 1.0000x reference)
//
#include <hip/hip_runtime.h>
#include <math.h>

#define BB 8
#define SS 32
#define HN 64
#define TN 512
#define HID 512

__device__ __forceinline__ float eluf(float x) { return x > 0.f ? x : (expf(x) - 1.f); }

// ---------------------------------------------------------------------------
// Generic tiled fp32 GEMM: C[M,N] = act(A@W + bias)
// A rows optionally gathered via ridx (embedding lookup). BM=BN=64, BK=16,
// 256 threads (16x16), 4x4 micro-tile per thread. M%64==0, N%64==0, K%16==0.
// ---------------------------------------------------------------------------
template <int ACT> // 0 = none, 1 = elu
__global__ __launch_bounds__(256) void gemm64(
    const float* __restrict__ A, const int* __restrict__ ridx, int lda,
    const float* __restrict__ W, int ldw,
    const float* __restrict__ bias,
    float* __restrict__ C, int ldc, int K)
{
    __shared__ float As[16][64];
    __shared__ float Ws[16][64];
    const int tx = threadIdx.x, ty = threadIdx.y;
    const int tid = ty * 16 + tx;
    const int m0 = blockIdx.y * 64, n0 = blockIdx.x * 64;
    float acc[4][4] = {};

    const int am = tid >> 2;        // 0..63 : A row within tile
    const int ak = (tid & 3) * 4;   // 0,4,8,12 : A k-offset
    const int wk = tid >> 4;        // 0..15 : W row within tile
    const int wc = (tid & 15) * 4;  // col offset

    const int r = m0 + am;
    const int rr = ridx ? ridx[r] : r;
    const float* arow = A + (long)rr * lda;

    for (int kt = 0; kt < K; kt += 16) {
        float4 av = *(const float4*)(arow + kt + ak);
        float4 wv = *(const float4*)(W + (long)(kt + wk) * ldw + n0 + wc);
        __syncthreads();
        As[ak + 0][am] = av.x; As[ak + 1][am] = av.y;
        As[ak + 2][am] = av.z; As[ak + 3][am] = av.w;
        *(float4*)&Ws[wk][wc] = wv;
        __syncthreads();
#pragma unroll
        for (int kk = 0; kk < 16; ++kk) {
            float4 a4 = *(float4*)&As[kk][ty * 4];
            float4 w4 = *(float4*)&Ws[kk][tx * 4];
            acc[0][0] += a4.x * w4.x; acc[0][1] += a4.x * w4.y; acc[0][2] += a4.x * w4.z; acc[0][3] += a4.x * w4.w;
            acc[1][0] += a4.y * w4.x; acc[1][1] += a4.y * w4.y; acc[1][2] += a4.y * w4.z; acc[1][3] += a4.y * w4.w;
            acc[2][0] += a4.z * w4.x; acc[2][1] += a4.z * w4.y; acc[2][2] += a4.z * w4.z; acc[2][3] += a4.z * w4.w;
            acc[3][0] += a4.w * w4.x; acc[3][1] += a4.w * w4.y; acc[3][2] += a4.w * w4.z; acc[3][3] += a4.w * w4.w;
        }
    }
#pragma unroll
    for (int i = 0; i < 4; ++i) {
        int row = m0 + ty * 4 + i;
        int col = n0 + tx * 4;
        float4 v = make_float4(acc[i][0], acc[i][1], acc[i][2], acc[i][3]);
        if (bias) { v.x += bias[col]; v.y += bias[col + 1]; v.z += bias[col + 2]; v.w += bias[col + 3]; }
        if (ACT == 1) { v.x = eluf(v.x); v.y = eluf(v.y); v.z = eluf(v.z); v.w = eluf(v.w); }
        *(float4*)(C + (long)row * ldc + col) = v;
    }
}

// ---------------------------------------------------------------------------
// graph_hid = tanh(ctx @ W_tout[:512] + tq @ W_tout[512:]) where tq is
// recomputed on the fly from qd/qh/qe/b_tq.  M=16384, N=512, K=512 twice.
// ---------------------------------------------------------------------------
__global__ __launch_bounds__(256) void gemm_graphhid(
    const float* __restrict__ ctx, const float* __restrict__ qd,
    const float* __restrict__ qh, const float* __restrict__ qe,
    const float* __restrict__ b_tq, const float* __restrict__ Wt,
    float* __restrict__ gh)
{
    __shared__ float As[16][64];
    __shared__ float Ws[16][64];
    const int tx = threadIdx.x, ty = threadIdx.y;
    const int tid = ty * 16 + tx;
    const int m0 = blockIdx.y * 64, n0 = blockIdx.x * 64;
    float acc[4][4] = {};

    const int am = tid >> 2;
    const int ak = (tid & 3) * 4;
    const int wk = tid >> 4;
    const int wc = (tid & 15) * 4;

    const int r = m0 + am;                 // row in (B, 2048)
    const int b = r >> 11, q = r & 2047;
    const int s = q >> 6, h = q & 63;
    const float* ctxr = ctx + (long)r * HID;
    const float* qdr = qd + (long)(b * SS + s) * HID;
    const float* qhr = qh + (long)b * HID;
    const float* qer = qe + (long)(b * HN + h) * HID;

    // pass A: ctx @ Wt[0:512]
    for (int kt = 0; kt < HID; kt += 16) {
        float4 av = *(const float4*)(ctxr + kt + ak);
        float4 wv = *(const float4*)(Wt + (long)(kt + wk) * HID + n0 + wc);
        __syncthreads();
        As[ak + 0][am] = av.x; As[ak + 1][am] = av.y;
        As[ak + 2][am] = av.z; As[ak + 3][am] = av.w;
        *(float4*)&Ws[wk][wc] = wv;
        __syncthreads();
#pragma unroll
        for (int kk = 0; kk < 16; ++kk) {
            float4 a4 = *(float4*)&As[kk][ty * 4];
            float4 w4 = *(float4*)&Ws[kk][tx * 4];
            acc[0][0] += a4.x * w4.x; acc[0][1] += a4.x * w4.y; acc[0][2] += a4.x * w4.z; acc[0][3] += a4.x * w4.w;
            acc[1][0] += a4.y * w4.x; acc[1][1] += a4.y * w4.y; acc[1][2] += a4.y * w4.z; acc[1][3] += a4.y * w4.w;
            acc[2][0] += a4.z * w4.x; acc[2][1] += a4.z * w4.y; acc[2][2] += a4.z * w4.z; acc[2][3] += a4.z * w4.w;
            acc[3][0] += a4.w * w4.x; acc[3][1] += a4.w * w4.y; acc[3][2] += a4.w * w4.z; acc[3][3] += a4.w * w4.w;
        }
    }
    // pass B: tq @ Wt[512:1024], tq recomputed with elu
    const float* Wt2 = Wt + (long)HID * HID;
    for (int kt = 0; kt < HID; kt += 16) {
        float4 a1 = *(const float4*)(qdr + kt + ak);
        float4 a2 = *(const float4*)(qhr + kt + ak);
        float4 a3 = *(const float4*)(qer + kt + ak);
        float4 bb = *(const float4*)(b_tq + kt + ak);
        float4 av;
        av.x = eluf(a1.x + a2.x + a3.x + bb.x);
        av.y = eluf(a1.y + a2.y + a3.y + bb.y);
        av.z = eluf(a1.z + a2.z + a3.z + bb.z);
        av.w = eluf(a1.w + a2.w + a3.w + bb.w);
        float4 wv = *(const float4*)(Wt2 + (long)(kt + wk) * HID + n0 + wc);
        __syncthreads();
        As[ak + 0][am] = av.x; As[ak + 1][am] = av.y;
        As[ak + 2][am] = av.z; As[ak + 3][am] = av.w;
        *(float4*)&Ws[wk][wc] = wv;
        __syncthreads();
#pragma unroll
        for (int kk = 0; kk < 16; ++kk) {
            float4 a4 = *(float4*)&As[kk][ty * 4];
            float4 w4 = *(float4*)&Ws[kk][tx * 4];
            acc[0][0] += a4.x * w4.x; acc[0][1] += a4.x * w4.y; acc[0][2] += a4.x * w4.z; acc[0][3] += a4.x * w4.w;
            acc[1][0] += a4.y * w4.x; acc[1][1] += a4.y * w4.y; acc[1][2] += a4.y * w4.z; acc[1][3] += a4.y * w4.w;
            acc[2][0] += a4.z * w4.x; acc[2][1] += a4.z * w4.y; acc[2][2] += a4.z * w4.z; acc[2][3] += a4.z * w4.w;
            acc[3][0] += a4.w * w4.x; acc[3][1] += a4.w * w4.y; acc[3][2] += a4.w * w4.z; acc[3][3] += a4.w * w4.w;
        }
    }
#pragma unroll
    for (int i = 0; i < 4; ++i) {
        int row = m0 + ty * 4 + i;
        int col = n0 + tx * 4;
        float4 v = make_float4(tanhf(acc[i][0]), tanhf(acc[i][1]), tanhf(acc[i][2]), tanhf(acc[i][3]));
        *(float4*)(gh + (long)row * HID + col) = v;
    }
}

// ---------------------------------------------------------------------------
// Fused tail attention: per block, 8 q-rows (same s, h0..h0+7) of one batch.
// scores -> mask -> softmax -> store tail_attn -> ctx = attn @ tk
// ---------------------------------------------------------------------------
__global__ __launch_bounds__(256) void attn_kernel(
    const float* __restrict__ qd, const float* __restrict__ qh,
    const float* __restrict__ qe, const float* __restrict__ b_tq,
    const float* __restrict__ tk, const int* __restrict__ adj,
    const int* __restrict__ dup, float* __restrict__ ta,
    float* __restrict__ ctx)
{
    const int b = blockIdx.y;
    const int q0 = blockIdx.x * 8;
    const int s = q0 >> 6, h0 = q0 & 63;
    const int tid = threadIdx.x;

    __shared__ float tq8[8][HID];
    __shared__ float sc[8][TN];

    // build 8 tq rows: elu(qd[b,s] + qh[b] + qe[b,h0+qi] + b_tq)
    for (int e = tid; e < 8 * HID; e += 256) {
        int qi = e >> 9, j = e & 511;
        float v = qd[(long)(b * SS + s) * HID + j] + qh[(long)b * HID + j] +
                  qe[(long)(b * HN + h0 + qi) * HID + j] + b_tq[j];
        tq8[qi][j] = eluf(v);
    }
    __syncthreads();

    const float* tkb = tk + (long)b * TN * HID;

    // scores: thread owns one t per rep, dots against all 8 tq rows
    for (int rep = 0; rep < 2; ++rep) {
        int t = rep * 256 + tid;
        const float* tkr = tkb + (long)t * HID;
        float acc[8] = {};
        for (int j0 = 0; j0 < HID; j0 += 4) {
            float4 kv = *(const float4*)(tkr + j0);
#pragma unroll
            for (int qi = 0; qi < 8; ++qi) {
                float4 tv = *(const float4*)&tq8[qi][j0];
                acc[qi] += kv.x * tv.x + kv.y * tv.y + kv.z * tv.z + kv.w * tv.w;
            }
        }
        int dupv = dup[(long)(b * SS + s) * TN + t];
#pragma unroll
        for (int qi = 0; qi < 8; ++qi) {
            int adjv = adj[(long)(b * HN + h0 + qi) * TN + t];
            sc[qi][t] = (adjv && !dupv) ? acc[qi] : -INFINITY;
        }
    }
    __syncthreads();

    // softmax: 32 lanes per row (8 rows in parallel)
    {
        const int g = tid >> 5, l = tid & 31;
        float m = -INFINITY;
#pragma unroll
        for (int i = 0; i < 16; ++i) m = fmaxf(m, sc[g][l + 32 * i]);
#pragma unroll
        for (int d = 16; d >= 1; d >>= 1) m = fmaxf(m, __shfl_xor(m, d));
        float ev[16];
        float sum = 0.f;
#pragma unroll
        for (int i = 0; i < 16; ++i) {
            float e = expf(sc[g][l + 32 * i] - m);
            ev[i] = e; sum += e;
        }
#pragma unroll
        for (int d = 16; d >= 1; d >>= 1) sum += __shfl_xor(sum, d);
        float inv = 1.f / sum;
#pragma unroll
        for (int i = 0; i < 16; ++i) {
            float a = ev[i] * inv;
            int t = l + 32 * i;
            sc[g][t] = a;
            ta[((long)b * 2048 + q0 + g) * TN + t] = a;
        }
    }
    __syncthreads();

    // ctx = attn @ tk : thread owns columns j, j+256
    {
        float acc1[8] = {}, acc2[8] = {};
        const int j1 = tid, j2 = tid + 256;
        for (int t = 0; t < TN; ++t) {
            float k1 = tkb[(long)t * HID + j1];
            float k2 = tkb[(long)t * HID + j2];
#pragma unroll
            for (int qi = 0; qi < 8; ++qi) {
                float a = sc[qi][t];
                acc1[qi] += a * k1;
                acc2[qi] += a * k2;
            }
        }
#pragma unroll
        for (int qi = 0; qi < 8; ++qi) {
            ctx[((long)b * 2048 + q0 + qi) * HID + j1] = acc1[qi];
            ctx[((long)b * 2048 + q0 + qi) * HID + j2] = acc2[qi];
        }
    }
}

// out[b,j] = sum_k in[b,k] * W[k,j]   (8x512 @ 512x512)
__global__ void matvec8(const float* __restrict__ in, const float* __restrict__ W,
                        float* __restrict__ out)
{
    const int b = blockIdx.x, tid = threadIdx.x;
    float a1 = 0.f, a2 = 0.f;
    for (int k = 0; k < HID; ++k) {
        float iv = in[b * HID + k];
        a1 += iv * W[(long)k * HID + tid];
        a2 += iv * W[(long)k * HID + tid + 256];
    }
    out[b * HID + tid] = a1;
    out[b * HID + tid + 256] = a2;
}

// hq = elu(hq_part + hq2[b] + b_hq)
__global__ void finish_hq(const float* __restrict__ part, const float* __restrict__ hq2,
                          const float* __restrict__ b_hq, float* __restrict__ hq)
{
    int idx = blockIdx.x * 256 + threadIdx.x;   // 131072
    int n = idx >> 9, j = idx & 511;
    int b = n >> 5;
    hq[idx] = eluf(part[idx] + hq2[b * HID + j] + b_hq[j]);
}

// hscores[n,k] = hq[n,:] . hk[n*64+k,:]   one wave per (n,k)
__global__ void hscores_kernel(const float* __restrict__ hq, const float* __restrict__ hk,
                               float* __restrict__ hs)
{
    const int rk = blockIdx.x;      // n*64+k
    const int n = rk >> 6;
    const int l = threadIdx.x;      // 64
    const float* hkr = hk + (long)rk * HID;
    const float* hqr = hq + (long)n * HID;
    float acc = 0.f;
#pragma unroll
    for (int i = 0; i < 8; ++i) {
        int d = l + 64 * i;
        acc += hqr[d] * hkr[d];
    }
#pragma unroll
    for (int d = 32; d >= 1; d >>= 1) acc += __shfl_xor(acc, d);
    if (l == 0) hs[rk] = acc;
}

// head softmax with length mask; one wave per n
__global__ void head_softmax_kernel(const int* __restrict__ head, const float* __restrict__ hs,
                                    float* __restrict__ ha)
{
    const int n = blockIdx.x;   // 256
    const int b = n >> 5;
    const int l = threadIdx.x;  // 64
    int hv = head[b * HN + l];
    unsigned long long ball = __ballot(hv != 0);
    int len = __popcll(ball);
    float scv = (l < len) ? hs[n * HN + l] : -INFINITY;
    float m = scv;
#pragma unroll
    for (int d = 32; d >= 1; d >>= 1) m = fmaxf(m, __shfl_xor(m, d));
    float e = expf(scv - m);
    float sum = e;
#pragma unroll
    for (int d = 32; d >= 1; d >>= 1) sum += __shfl_xor(sum, d);
    ha[n * HN + l] = e / sum;
}

// out[n,t] = log(sum_k ha[n,k] * ta[b, s*64+k, t] + 1e-20)
__global__ void prob_kernel(const float* __restrict__ ha, const float* __restrict__ ta,
                            float* __restrict__ out)
{
    const int n = blockIdx.x;   // 256
    const int b = n >> 5, s = n & 31;
    const int tid = threadIdx.x;
    __shared__ float hal[HN];
    if (tid < HN) hal[tid] = ha[n * HN + tid];
    __syncthreads();
    const float* tab = ta + ((long)b * 2048 + s * 64) * TN;
    for (int t = tid; t < TN; t += 256) {
        float acc = 0.f;
        for (int k = 0; k < HN; ++k) acc += hal[k] * tab[(long)k * TN + t];
        out[(long)n * TN + t] = logf(acc + 1e-20f);
    }
}

extern "C" void kernel_launch(void* const* d_in, const int* in_sizes, int n_in,
                              void* d_out, int out_size, void* d_ws, size_t ws_size,
                              hipStream_t stream)
{
    const float* dec_out = (const float*)d_in[0];
    const float* history = (const float*)d_in[1];
    const int*   head    = (const int*)d_in[2];
    const int*   tail    = (const int*)d_in[3];
    const int*   adj     = (const int*)d_in[4];
    const int*   dup     = (const int*)d_in[5];
    const float* emb     = (const float*)d_in[6];
    const float* W_tq    = (const float*)d_in[7];
    const float* b_tq    = (const float*)d_in[8];
    const float* W_tk    = (const float*)d_in[9];
    const float* b_tk    = (const float*)d_in[10];
    const float* W_tout  = (const float*)d_in[11];
    const float* W_hq    = (const float*)d_in[12];
    const float* b_hq    = (const float*)d_in[13];
    const float* W_hk    = (const float*)d_in[14];
    const float* b_hk    = (const float*)d_in[15];
    float* out = (float*)d_out;

    char* ws = (char*)d_ws;
    auto alloc = [&](size_t bytes) -> float* {
        char* p = ws;
        ws += (bytes + 255) & ~(size_t)255;
        return (float*)p;
    };
    float* qd  = alloc((size_t)256 * 512 * 4);
    float* qh  = alloc((size_t)8 * 512 * 4);
    float* qe  = alloc((size_t)512 * 512 * 4);
    float* tk  = alloc((size_t)4096 * 512 * 4);
    float* hq2 = alloc((size_t)8 * 512 * 4);
    float* hqp = alloc((size_t)256 * 512 * 4);
    float* hq  = alloc((size_t)256 * 512 * 4);
    float* ta  = alloc((size_t)16384 * 512 * 4);
    float* ctx = alloc((size_t)16384 * 512 * 4);
    float* gh  = alloc((size_t)16384 * 512 * 4);
    float* hk  = ctx;  // ctx is dead once gh is computed
    float* hs  = alloc((size_t)16384 * 4);
    float* ha  = alloc((size_t)16384 * 4);

    dim3 thr(16, 16);
    // qd = dec_out @ W_tq[0:512]
    gemm64<0><<<dim3(8, 4), thr, 0, stream>>>(dec_out, nullptr, 512, W_tq, 512, nullptr, qd, 512, 512);
    // qh = history @ W_tq[512:1024]
    matvec8<<<8, 256, 0, stream>>>(history, W_tq + 512 * 512, qh);
    // qe = emb[head] @ W_tq[1024:1536]
    gemm64<0><<<dim3(8, 8), thr, 0, stream>>>(emb, head, 512, W_tq + 1024 * 512, 512, nullptr, qe, 512, 512);
    // tk = elu(emb[tail] @ W_tk + b_tk)
    gemm64<1><<<dim3(8, 64), thr, 0, stream>>>(emb, tail, 512, W_tk, 512, b_tk, tk, 512, 512);
    // hq = elu(dec_out @ W_hq[:512] + history @ W_hq[512:] + b_hq)
    gemm64<0><<<dim3(8, 4), thr, 0, stream>>>(dec_out, nullptr, 512, W_hq, 512, nullptr, hqp, 512, 512);
    matvec8<<<8, 256, 0, stream>>>(history, W_hq + 512 * 512, hq2);
    finish_hq<<<512, 256, 0, stream>>>(hqp, hq2, b_hq, hq);
    // fused tail attention -> ta, ctx
    attn_kernel<<<dim3(256, BB), 256, 0, stream>>>(qd, qh, qe, b_tq, tk, adj, dup, ta, ctx);
    // graph_hid = tanh(ctx @ W_tout[:512] + tq @ W_tout[512:])
    gemm_graphhid<<<dim3(8, 256), thr, 0, stream>>>(ctx, qd, qh, qe, b_tq, W_tout, gh);
    // hk = elu(gh @ W_hk + b_hk)  (reuses ctx buffer)
    gemm64<1><<<dim3(8, 256), thr, 0, stream>>>(gh, nullptr, 512, W_hk, 512, b_hk, hk, 512, 512);
    // hscores, head softmax, final prob
    hscores_kernel<<<16384, 64, 0, stream>>>(hq, hk, hs);
    head_softmax_kernel<<<256, 64, 0, stream>>>(head, hs, ha);
    prob_kernel<<<256, 256, 0, stream>>>(ha, ta, out);
}

// Round 2
// 392.053 us; speedup vs baseline: 2.9638x; 2.9638x over previous
//
#include <hip/hip_runtime.h>
#include <math.h>

#define BB 8
#define SS 32
#define HN 64
#define TN 512
#define HID 512

typedef __attribute__((ext_vector_type(8))) short short8;
typedef __attribute__((ext_vector_type(4))) float f32x4;

__device__ __forceinline__ float eluf(float x) { return x > 0.f ? x : (expf(x) - 1.f); }

// fp32 -> bf16 round-to-nearest-even (raw bits; avoids header API drift)
__device__ __forceinline__ short f2bs(float f) {
    union { float f; unsigned int u; } v; v.f = f;
    unsigned int r = v.u + 0x7fffu + ((v.u >> 16) & 1u);
    return (short)(r >> 16);
}
__device__ __forceinline__ float b2f(short s) {
    union { unsigned int u; float f; } v;
    v.u = ((unsigned int)(unsigned short)s) << 16;
    return v.f;
}

// ---------------------------------------------------------------------------
// Universal bf16 MFMA GEMM:  C[M][N] = act( A[M][K] @ B[N][K]^T (+ A2@B2^T) + bias )
// 128x128 tile, BK=32, 256 threads = 4 waves, each wave 64x64 (4x4 MFMA frags).
// M % 128 == 0, N % 128 == 0, K % 32 == 0.  Optional z-batching via strides.
// ACT: 0=none 1=elu 2=tanh.  OUTB: 1=bf16 out, 0=f32 out.
// MASKED: scores epilogue (adj & ~dup -> -inf), row r -> s=r>>6, h=r&63, z=b.
// ---------------------------------------------------------------------------
template <int ACT, int OUTB, int MASKED, int DUAL>
__global__ __launch_bounds__(256) void mgemm(
    const short* __restrict__ A, long sAz,
    const short* __restrict__ B, long sBz,
    const short* __restrict__ A2, const short* __restrict__ B2,
    const float* __restrict__ bias,
    void* __restrict__ Cv, long sCz, int ldc, int K,
    const int* __restrict__ adj, const int* __restrict__ dup)
{
    __shared__ short Al[128][40];   // 32 + 8 pad (bank spread, keeps 16B align)
    __shared__ short Bl[128][40];
    const int tid  = threadIdx.x;
    const int lane = tid & 63;
    const int w    = tid >> 6;
    const int wr   = w >> 1, wc = w & 1;
    const int l16  = lane & 15, quad = lane >> 4;
    const int m0 = blockIdx.y * 128, n0 = blockIdx.x * 128;
    const int z  = blockIdx.z;

    const int srow = tid >> 1;            // 0..127 staged row
    const int scol = (tid & 1) * 16;      // short offset 0 / 16

    f32x4 acc[4][4];
#pragma unroll
    for (int i = 0; i < 4; ++i)
#pragma unroll
        for (int j = 0; j < 4; ++j) { acc[i][j][0]=0.f; acc[i][j][1]=0.f; acc[i][j][2]=0.f; acc[i][j][3]=0.f; }

    for (int rep = 0; rep <= DUAL; ++rep) {
        const short* Ag = (rep ? A2 : A) + (long)z * sAz + (long)(m0 + srow) * K + scol;
        const short* Bg = (rep ? B2 : B) + (long)z * sBz + (long)(n0 + srow) * K + scol;
        for (int kt = 0; kt < K; kt += 32) {
            int4 a0 = *(const int4*)(Ag + kt);
            int4 a1 = *(const int4*)(Ag + kt + 8);
            int4 b0 = *(const int4*)(Bg + kt);
            int4 b1 = *(const int4*)(Bg + kt + 8);
            __syncthreads();
            *(int4*)&Al[srow][scol]     = a0;
            *(int4*)&Al[srow][scol + 8] = a1;
            *(int4*)&Bl[srow][scol]     = b0;
            *(int4*)&Bl[srow][scol + 8] = b1;
            __syncthreads();
            short8 af[4], bf[4];
#pragma unroll
            for (int mi = 0; mi < 4; ++mi)
                af[mi] = *(const short8*)&Al[wr * 64 + mi * 16 + l16][quad * 8];
#pragma unroll
            for (int ni = 0; ni < 4; ++ni)
                bf[ni] = *(const short8*)&Bl[wc * 64 + ni * 16 + l16][quad * 8];
#pragma unroll
            for (int mi = 0; mi < 4; ++mi)
#pragma unroll
                for (int ni = 0; ni < 4; ++ni)
                    acc[mi][ni] = __builtin_amdgcn_mfma_f32_16x16x32_bf16(af[mi], bf[ni], acc[mi][ni], 0, 0, 0);
        }
    }

#pragma unroll
    for (int mi = 0; mi < 4; ++mi)
#pragma unroll
        for (int ni = 0; ni < 4; ++ni) {
            int gr0 = m0 + wr * 64 + mi * 16 + quad * 4;
            int gc  = n0 + wc * 64 + ni * 16 + l16;
#pragma unroll
            for (int r = 0; r < 4; ++r) {
                float x = acc[mi][ni][r];
                int gr = gr0 + r;
                if (bias) x += bias[gc];
                if (MASKED) {
                    int s = gr >> 6, h = gr & 63;
                    bool ok = adj[((long)(z * 64 + h)) * 512 + gc] && !dup[((long)(z * 32 + s)) * 512 + gc];
                    if (!ok) x = -INFINITY;
                }
                if (ACT == 1) x = eluf(x);
                else if (ACT == 2) x = tanhf(x);
                long ci = (long)z * sCz + (long)gr * ldc + gc;
                if (OUTB) ((short*)Cv)[ci] = f2bs(x);
                else      ((float*)Cv)[ci] = x;
            }
        }
}

// ---------------------------------------------------------------------------
// fp32->bf16 cast of dec_out (131072 elems)
__global__ void cast_dec(const float* __restrict__ src, short* __restrict__ dst) {
    int i = blockIdx.x * 256 + threadIdx.x;
    dst[i] = f2bs(src[i]);
}

// gather+cast emb rows: r<512 -> head, else tail
__global__ void gather_cast(const float* __restrict__ emb, const int* __restrict__ head,
                            const int* __restrict__ tail, short* __restrict__ he, short* __restrict__ te)
{
    int r = blockIdx.x, t = threadIdx.x;
    int idx; short* dst;
    if (r < 512) { idx = head[r]; dst = he + (long)r * 512; }
    else         { idx = tail[r - 512]; dst = te + (long)(r - 512) * 512; }
    const float* s = emb + (long)idx * 512;
    dst[t]       = f2bs(s[t]);
    dst[t + 256] = f2bs(s[t + 256]);
}

// batched 512x512 transpose-cast: WT[n][k] = bf16(W[k][n]); z selects matrix
struct WTDesc { const float* src[8]; short* dst[8]; };
__global__ void transW(WTDesc d) {
    __shared__ float t[32][33];
    const float* src = d.src[blockIdx.z];
    short* dst = d.dst[blockIdx.z];
    int k0 = blockIdx.y * 32, n0 = blockIdx.x * 32;
    int tx = threadIdx.x & 31, ty = threadIdx.x >> 5;  // 32x8
#pragma unroll
    for (int i = 0; i < 32; i += 8)
        t[ty + i][tx] = src[(long)(k0 + ty + i) * 512 + n0 + tx];
    __syncthreads();
#pragma unroll
    for (int i = 0; i < 32; i += 8)
        dst[(long)(n0 + ty + i) * 512 + k0 + tx] = f2bs(t[tx][ty + i]);
}

// bf16 per-b 512x512 transpose: tkT[b][h][t] = tk[b][t][h]
__global__ void trans_tk(const short* __restrict__ tk, short* __restrict__ tkT) {
    __shared__ short t[32][33];
    const short* src = tk + (long)blockIdx.z * 262144;
    short* dst = tkT + (long)blockIdx.z * 262144;
    int t0 = blockIdx.y * 32, h0 = blockIdx.x * 32;
    int tx = threadIdx.x & 31, ty = threadIdx.x >> 5;
#pragma unroll
    for (int i = 0; i < 32; i += 8)
        t[ty + i][tx] = src[(long)(t0 + ty + i) * 512 + h0 + tx];
    __syncthreads();
#pragma unroll
    for (int i = 0; i < 32; i += 8)
        dst[(long)(h0 + ty + i) * 512 + t0 + tx] = t[tx][ty + i];
}

// qh / hq2: history(8x512) @ W(512x512), fp32, y selects which
__global__ void matvec_pair(const float* __restrict__ hist, const float* __restrict__ Wtq,
                            const float* __restrict__ Whq, float* __restrict__ qh, float* __restrict__ hq2)
{
    const float* W = blockIdx.y ? Whq : Wtq;
    float* out = blockIdx.y ? hq2 : qh;
    int b = blockIdx.x, t = threadIdx.x;
    float a1 = 0.f, a2 = 0.f;
    for (int k = 0; k < HID; ++k) {
        float iv = hist[b * HID + k];
        a1 += iv * W[(long)k * HID + t];
        a2 += iv * W[(long)k * HID + t + 256];
    }
    out[b * HID + t] = a1;
    out[b * HID + t + 256] = a2;
}

// tq_bf16[b, s*64+h, :] = bf16(elu(qd[b,s] + qh[b] + qe[b,h] + b_tq))
__global__ void build_tq(const float* __restrict__ qdhq, const float* __restrict__ qh,
                         const float* __restrict__ qe, const float* __restrict__ b_tq,
                         short* __restrict__ tqb)
{
    long gid = (long)blockIdx.x * 256 + threadIdx.x;   // 16384*128 total
    int r = (int)(gid >> 7), j0 = ((int)gid & 127) * 4;
    int b = r >> 11, rem = r & 2047, s = rem >> 6, h = rem & 63;
    float4 d = *(const float4*)(qdhq + (long)(b * 32 + s) * 1024 + j0);
    float4 q = *(const float4*)(qh + (long)b * 512 + j0);
    float4 e = *(const float4*)(qe + (long)(b * 64 + h) * 512 + j0);
    float4 bb = *(const float4*)(b_tq + j0);
    short4 o;
    o.x = f2bs(eluf(d.x + q.x + e.x + bb.x));
    o.y = f2bs(eluf(d.y + q.y + e.y + bb.y));
    o.z = f2bs(eluf(d.z + q.z + e.z + bb.z));
    o.w = f2bs(eluf(d.w + q.w + e.w + bb.w));
    *(short4*)(tqb + (long)r * 512 + j0) = o;
}

// row softmax over 512, in-place (scores -> tail_attn fp32) + bf16 copy
__global__ __launch_bounds__(256) void sm_kernel(float* __restrict__ sc, short* __restrict__ Pb) {
    int w = threadIdx.x >> 6, lane = threadIdx.x & 63;
    long r = (long)blockIdx.x * 4 + w;
    float* row = sc + r * 512;
    float v[8];
    float m = -INFINITY;
#pragma unroll
    for (int i = 0; i < 8; ++i) { v[i] = row[lane + 64 * i]; m = fmaxf(m, v[i]); }
#pragma unroll
    for (int d = 32; d >= 1; d >>= 1) m = fmaxf(m, __shfl_xor(m, d));
    float sum = 0.f;
#pragma unroll
    for (int i = 0; i < 8; ++i) {
        float e = (m == -INFINITY) ? 0.f : expf(v[i] - m);
        v[i] = e; sum += e;
    }
#pragma unroll
    for (int d = 32; d >= 1; d >>= 1) sum += __shfl_xor(sum, d);
    float inv = sum > 0.f ? 1.f / sum : 0.f;
#pragma unroll
    for (int i = 0; i < 8; ++i) {
        float a = v[i] * inv;
        int t = lane + 64 * i;
        row[t] = a;
        Pb[r * 512 + t] = f2bs(a);
    }
}

// hq build + hscores + head softmax + prob + log, one block per n (=b*32+s)
__global__ __launch_bounds__(256) void fused_head(
    const float* __restrict__ qdhq, const float* __restrict__ hq2, const float* __restrict__ b_hq,
    const short* __restrict__ hk, const int* __restrict__ head,
    const float* __restrict__ ta, float* __restrict__ out)
{
    int n = blockIdx.x, b = n >> 5;
    int tid = threadIdx.x;
    __shared__ float hql[512];
    __shared__ float hsl[64];
    __shared__ float hal[64];

    for (int j = tid; j < 512; j += 256)
        hql[j] = eluf(qdhq[(long)n * 1024 + 512 + j] + hq2[b * 512 + j] + b_hq[j]);
    __syncthreads();

    {   // hscores: 4 threads per k
        int k = tid >> 2, p = tid & 3;
        const short* hkr = hk + ((long)n * 64 + k) * 512 + p * 128;
        const float* hq0 = hql + p * 128;
        float a = 0.f;
        for (int j = 0; j < 128; ++j) a += hq0[j] * b2f(hkr[j]);
        a += __shfl_xor(a, 1);
        a += __shfl_xor(a, 2);
        if (p == 0) hsl[k] = a;
    }
    __syncthreads();

    if (tid < 64) {   // wave 0: length-masked softmax over 64 heads
        int hv = head[b * 64 + tid];
        unsigned long long ball = __ballot(hv != 0);
        int len = __popcll(ball);
        float sv = (tid < len) ? hsl[tid] : -INFINITY;
        float m = sv;
#pragma unroll
        for (int d = 32; d >= 1; d >>= 1) m = fmaxf(m, __shfl_xor(m, d));
        float e = expf(sv - m);
        float sum = e;
#pragma unroll
        for (int d = 32; d >= 1; d >>= 1) sum += __shfl_xor(sum, d);
        hal[tid] = e / sum;
    }
    __syncthreads();

    const float* tab = ta + (long)n * 64 * 512;
    for (int t = tid; t < 512; t += 256) {
        float a = 0.f;
        for (int k = 0; k < 64; ++k) a += hal[k] * tab[(long)k * 512 + t];
        out[(long)n * 512 + t] = logf(a + 1e-20f);
    }
}

extern "C" void kernel_launch(void* const* d_in, const int* in_sizes, int n_in,
                              void* d_out, int out_size, void* d_ws, size_t ws_size,
                              hipStream_t stream)
{
    const float* dec_out = (const float*)d_in[0];
    const float* history = (const float*)d_in[1];
    const int*   head    = (const int*)d_in[2];
    const int*   tail    = (const int*)d_in[3];
    const int*   adj     = (const int*)d_in[4];
    const int*   dup     = (const int*)d_in[5];
    const float* emb     = (const float*)d_in[6];
    const float* W_tq    = (const float*)d_in[7];
    const float* b_tq    = (const float*)d_in[8];
    const float* W_tk    = (const float*)d_in[9];
    const float* b_tk    = (const float*)d_in[10];
    const float* W_tout  = (const float*)d_in[11];
    const float* W_hq    = (const float*)d_in[12];
    const float* b_hq    = (const float*)d_in[13];
    const float* W_hk    = (const float*)d_in[14];
    const float* b_hk    = (const float*)d_in[15];
    float* out = (float*)d_out;

    char* ws = (char*)d_ws;
    auto alloc = [&](size_t bytes) -> void* {
        char* p = ws;
        ws += (bytes + 255) & ~(size_t)255;
        return (void*)p;
    };
    short* decb    = (short*)alloc(131072 * 2);
    short* headEmb = (short*)alloc(512 * 512 * 2);
    short* tailEmb = (short*)alloc(4096 * 512 * 2);
    short* WT      = (short*)alloc((size_t)7 * 512 * 512 * 2);
    float* qh      = (float*)alloc(8 * 512 * 4);
    float* hq2     = (float*)alloc(8 * 512 * 4);
    float* qdhq    = (float*)alloc((size_t)256 * 1024 * 4);
    float* qe      = (float*)alloc((size_t)512 * 512 * 4);
    short* tkb     = (short*)alloc((size_t)4096 * 512 * 2);
    short* tkTb    = (short*)alloc((size_t)4096 * 512 * 2);
    short* tqb     = (short*)alloc((size_t)16384 * 512 * 2);
    float* sc      = (float*)alloc((size_t)16384 * 512 * 4);   // scores, then tail_attn (in-place)
    short* Pb      = (short*)alloc((size_t)16384 * 512 * 2);   // P bf16, later reused as gh
    short* ctxb    = (short*)alloc((size_t)16384 * 512 * 2);   // ctx bf16, later reused as hk
    short* ghb = Pb;     // P dead after PV GEMM
    short* hkb = ctxb;   // ctx dead after gh GEMM

    // transposed-weight slab layout: [0]=W_tq[:512]^T, [1]=W_hq[:512]^T (contiguous
    // pair -> one [1024][512] B for the fused qd|hqp GEMM), [2]=W_tq[1024:]^T,
    // [3]=W_tk^T, [4]=W_tout[:512]^T, [5]=W_tout[512:]^T, [6]=W_hk^T
    short* WT0 = WT;
    short* WT2 = WT + (size_t)2 * 262144;
    short* WT3 = WT + (size_t)3 * 262144;
    short* WT4 = WT + (size_t)4 * 262144;
    short* WT5 = WT + (size_t)5 * 262144;
    short* WT6 = WT + (size_t)6 * 262144;

    cast_dec<<<512, 256, 0, stream>>>(dec_out, decb);
    gather_cast<<<4608, 256, 0, stream>>>(emb, head, tail, headEmb, tailEmb);

    WTDesc wd;
    wd.src[0] = W_tq;               wd.dst[0] = WT0;
    wd.src[1] = W_hq;               wd.dst[1] = WT + 262144;
    wd.src[2] = W_tq + 1024 * 512;  wd.dst[2] = WT2;
    wd.src[3] = W_tk;               wd.dst[3] = WT3;
    wd.src[4] = W_tout;             wd.dst[4] = WT4;
    wd.src[5] = W_tout + 512 * 512; wd.dst[5] = WT5;
    wd.src[6] = W_hk;               wd.dst[6] = WT6;
    wd.src[7] = W_tk;               wd.dst[7] = WT3;  // unused pad
    transW<<<dim3(16, 16, 7), 256, 0, stream>>>(wd);

    matvec_pair<<<dim3(8, 2), 256, 0, stream>>>(history, W_tq + 512 * 512, W_hq + 512 * 512, qh, hq2);

    // [qd | hqp] = dec_bf16 @ [Wd^T ; Whq1^T]^T   M=256 N=1024 K=512, fp32 out
    mgemm<0, 0, 0, 0><<<dim3(8, 2, 1), 256, 0, stream>>>(
        decb, 0, WT0, 0, nullptr, nullptr, nullptr, qdhq, 0, 1024, 512, nullptr, nullptr);
    // qe = head_emb @ We^T   M=512 N=512, fp32 out
    mgemm<0, 0, 0, 0><<<dim3(4, 4, 1), 256, 0, stream>>>(
        headEmb, 0, WT2, 0, nullptr, nullptr, nullptr, qe, 0, 512, 512, nullptr, nullptr);
    // tk = elu(tail_emb @ W_tk^T + b_tk)   M=4096, bf16 out
    mgemm<1, 1, 0, 0><<<dim3(4, 32, 1), 256, 0, stream>>>(
        tailEmb, 0, WT3, 0, nullptr, nullptr, b_tk, tkb, 0, 512, 512, nullptr, nullptr);

    build_tq<<<8192, 256, 0, stream>>>(qdhq, qh, qe, b_tq, tqb);

    // scores[b] = tq[b] @ tk[b]^T, masked -> fp32 scores buffer. z=b, M=2048/z
    mgemm<0, 0, 1, 0><<<dim3(4, 16, 8), 256, 0, stream>>>(
        tqb, 2048 * 512, tkb, 262144, nullptr, nullptr, nullptr, sc, 2048 * 512, 512, 512, adj, dup);

    sm_kernel<<<4096, 256, 0, stream>>>(sc, Pb);
    trans_tk<<<dim3(16, 16, 8), 256, 0, stream>>>(tkb, tkTb);

    // ctx[b] = P[b] @ tkT[b]^T   (NT with B=[h][t]), bf16 out
    mgemm<0, 1, 0, 0><<<dim3(4, 16, 8), 256, 0, stream>>>(
        Pb, 2048 * 512, tkTb, 262144, nullptr, nullptr, nullptr, ctxb, 2048 * 512, 512, 512, nullptr, nullptr);

    // gh = tanh(ctx @ Wtout1^T + tq @ Wtout2^T)   M=16384, dual-pass, bf16 out
    mgemm<2, 1, 0, 1><<<dim3(4, 128, 1), 256, 0, stream>>>(
        ctxb, 0, WT4, 0, tqb, WT5, nullptr, ghb, 0, 512, 512, nullptr, nullptr);

    // hk = elu(gh @ W_hk^T + b_hk)   M=16384, bf16 out
    mgemm<1, 1, 0, 0><<<dim3(4, 128, 1), 256, 0, stream>>>(
        ghb, 0, WT6, 0, nullptr, nullptr, b_hk, hkb, 0, 512, 512, nullptr, nullptr);

    fused_head<<<256, 256, 0, stream>>>(qdhq, hq2, b_hq, hkb, head, sc, out);
}

// Round 3
// 306.321 us; speedup vs baseline: 3.7933x; 1.2799x over previous
//
#include <hip/hip_runtime.h>
#include <math.h>

#define BB 8
#define SS 32
#define HN 64
#define TN 512
#define HID 512

typedef __attribute__((ext_vector_type(8))) short short8;
typedef __attribute__((ext_vector_type(4))) float f32x4;

__device__ __forceinline__ float eluf(float x) { return x > 0.f ? x : (expf(x) - 1.f); }

__device__ __forceinline__ short f2bs(float f) {
    union { float f; unsigned int u; } v; v.f = f;
    unsigned int r = v.u + 0x7fffu + ((v.u >> 16) & 1u);
    return (short)(r >> 16);
}
__device__ __forceinline__ float b2f(short s) {
    union { unsigned int u; float f; } v;
    v.u = ((unsigned int)(unsigned short)s) << 16;
    return v.f;
}

// async global->LDS, 16 bytes per lane. LDS dest = wave-uniform base + lane*16.
__device__ __forceinline__ void gld16(const void* g, void* l) {
    __builtin_amdgcn_global_load_lds(
        (const __attribute__((address_space(1))) void*)g,
        (__attribute__((address_space(3))) void*)l, 16, 0, 0);
}

// ---------------------------------------------------------------------------
// GEMM core (m97 structure): C[128x128 tile] = act(A@B^T (+A2@B2^T) + bias)
// A[M][K], B[N][K] bf16. LDS [128][32] contiguous (global_load_lds layout).
// 256 thr = 4 waves, wave = 64x64 via 4x4 mfma_f32_16x16x32_bf16.
// ACT: 0=none 1=elu 2=tanh. OUTB: 1=bf16 out else f32.
// m0 = A row base, cm0 = C row base (differ only for sliced outputs).
// ---------------------------------------------------------------------------
template <int ACT, int OUTB, int DUAL>
__device__ __forceinline__ void gcore(
    const short* __restrict__ A, const short* __restrict__ B,
    const short* __restrict__ A2, const short* __restrict__ B2,
    const float* __restrict__ bias, void* __restrict__ Cv,
    int ldc, int K, int m0, int n0, int cm0,
    short* Al, short* Bl)
{
    const int tid  = threadIdx.x;
    const int lane = tid & 63;
    const int w    = tid >> 6;
    const int wr   = w >> 1, wc = w & 1;
    const int l16  = lane & 15, quad = lane >> 4;

    // staging coords: wave w, lane l covers LDS bytes w*1024 + l*16 (and +4096)
    const int srow = w * 16 + (lane >> 2);   // row 0..63 (issue 0), +64 (issue 1)
    const int scol = (lane & 3) * 8;         // short offset within 32-wide row

    f32x4 acc[4][4];
#pragma unroll
    for (int i = 0; i < 4; ++i)
#pragma unroll
        for (int j = 0; j < 4; ++j) { acc[i][j][0]=0.f; acc[i][j][1]=0.f; acc[i][j][2]=0.f; acc[i][j][3]=0.f; }

    short* lA = Al + w * 512;   // w*1024 bytes
    short* lB = Bl + w * 512;
    const long rstep = (long)64 * K;

    for (int rep = 0; rep <= DUAL; ++rep) {
        const short* Ag = (rep ? A2 : A) + (long)(m0 + srow) * K + scol;
        const short* Bg = (rep ? B2 : B) + (long)(n0 + srow) * K + scol;
        for (int kt = 0; kt < K; kt += 32) {
            __syncthreads();                 // protect LDS from previous readers
            gld16(Ag + kt, lA);
            gld16(Ag + kt + rstep, lA + 2048);
            gld16(Bg + kt, lB);
            gld16(Bg + kt + rstep, lB + 2048);
            __syncthreads();                 // drains vmcnt: tiles landed
            short8 af[4], bf4[4];
#pragma unroll
            for (int mi = 0; mi < 4; ++mi)
                af[mi] = *(const short8*)(Al + (wr * 64 + mi * 16 + l16) * 32 + quad * 8);
#pragma unroll
            for (int ni = 0; ni < 4; ++ni)
                bf4[ni] = *(const short8*)(Bl + (wc * 64 + ni * 16 + l16) * 32 + quad * 8);
#pragma unroll
            for (int mi = 0; mi < 4; ++mi)
#pragma unroll
                for (int ni = 0; ni < 4; ++ni)
                    acc[mi][ni] = __builtin_amdgcn_mfma_f32_16x16x32_bf16(af[mi], bf4[ni], acc[mi][ni], 0, 0, 0);
        }
    }

#pragma unroll
    for (int mi = 0; mi < 4; ++mi)
#pragma unroll
        for (int ni = 0; ni < 4; ++ni) {
            int lr0 = wr * 64 + mi * 16 + quad * 4;
            int gc  = n0 + wc * 64 + ni * 16 + l16;
#pragma unroll
            for (int r = 0; r < 4; ++r) {
                float x = acc[mi][ni][r];
                if (bias) x += bias[gc];
                if (ACT == 1) x = eluf(x);
                else if (ACT == 2) x = tanhf(x);
                long ci = (long)(cm0 + lr0 + r) * ldc + gc;
                if (OUTB) ((short*)Cv)[ci] = f2bs(x);
                else      ((float*)Cv)[ci] = x;
            }
        }
}

template <int ACT, int OUTB, int DUAL>
__global__ __launch_bounds__(256) void mgemm(
    const short* __restrict__ A, long sAz,
    const short* __restrict__ B, long sBz,
    const short* __restrict__ A2, const short* __restrict__ B2,
    const float* __restrict__ bias,
    void* __restrict__ Cv, long sCz, int ldc, int K)
{
    __shared__ short Al[4096], Bl[4096];
    const int z = blockIdx.z;
    void* C = OUTB ? (void*)((short*)Cv + (long)z * sCz) : (void*)((float*)Cv + (long)z * sCz);
    gcore<ACT, OUTB, DUAL>(A + (long)z * sAz, B + (long)z * sBz, A2, B2, bias, C,
                           ldc, K, blockIdx.y * 128, blockIdx.x * 128, blockIdx.y * 128, Al, Bl);
}

// qdhq (16 blocks) | qe (16 blocks) | tk (128 blocks) in one launch
__global__ __launch_bounds__(256) void mgemm_multi(
    const short* __restrict__ decb, const short* __restrict__ WT0, float* __restrict__ qdhq,
    const short* __restrict__ embAll, const short* __restrict__ WT2, float* __restrict__ qe,
    const short* __restrict__ WT3, const float* __restrict__ b_tk, short* __restrict__ tkb)
{
    __shared__ short Al[4096], Bl[4096];
    int id = blockIdx.x;
    if (id < 16) {
        int x = id & 7, y = id >> 3;
        gcore<0, 0, 0>(decb, WT0, nullptr, nullptr, nullptr, qdhq, 1024, 512,
                       y * 128, x * 128, y * 128, Al, Bl);
    } else {
        int id2 = id - 16;
        int x = id2 & 3, y = id2 >> 2;
        if (y < 4)
            gcore<0, 0, 0>(embAll, WT2, nullptr, nullptr, nullptr, qe, 512, 512,
                           y * 128, x * 128, y * 128, Al, Bl);
        else
            gcore<1, 1, 0>(embAll, WT3, nullptr, nullptr, b_tk, tkb, 512, 512,
                           y * 128, x * 128, (y - 4) * 128, Al, Bl);
    }
}

// ---------------------------------------------------------------------------
// prep: cast dec_out | gather+cast emb rows | transpose-cast 7 weights | matvecs
// ---------------------------------------------------------------------------
struct WTDesc { const float* src[8]; short* dst[8]; };

__global__ __launch_bounds__(256) void prep(
    const float* __restrict__ dec_out, short* __restrict__ decb,
    const float* __restrict__ emb, const int* __restrict__ head, const int* __restrict__ tail,
    short* __restrict__ embAll, WTDesc wd,
    const float* __restrict__ hist, const float* __restrict__ Wtq2, const float* __restrict__ Whq2,
    float* __restrict__ qh, float* __restrict__ hq2)
{
    __shared__ float t[32][33];
    const int id = blockIdx.x, tid = threadIdx.x;
    if (id < 512) {                       // cast dec_out (131072 elems)
        int i = id * 256 + tid;
        decb[i] = f2bs(dec_out[i]);
    } else if (id < 512 + 4608) {         // gather+cast emb rows (head|tail)
        int r = id - 512;
        int idx = (r < 512) ? head[r] : tail[r - 512];
        const float* s = emb + (long)idx * 512;
        short* dst = embAll + (long)r * 512;
        dst[tid]       = f2bs(s[tid]);
        dst[tid + 256] = f2bs(s[tid + 256]);
    } else if (id < 512 + 4608 + 1792) {  // transpose-cast weights
        int q = id - 5120;
        int z = q >> 8, xy = q & 255;
        int x = xy & 15, y = xy >> 4;
        const float* src = wd.src[z];
        short* dst = wd.dst[z];
        int k0 = y * 32, n0 = x * 32;
        int tx = tid & 31, ty = tid >> 5;
#pragma unroll
        for (int i = 0; i < 32; i += 8)
            t[ty + i][tx] = src[(long)(k0 + ty + i) * 512 + n0 + tx];
        __syncthreads();
#pragma unroll
        for (int i = 0; i < 32; i += 8)
            dst[(long)(n0 + ty + i) * 512 + k0 + tx] = f2bs(t[tx][ty + i]);
    } else {                              // matvec: history @ W (2 of them)
        int id2 = id - 6912;              // 0..15
        int b = id2 & 7, sel = id2 >> 3;
        const float* W = sel ? Whq2 : Wtq2;
        float* o = sel ? hq2 : qh;
        float a1 = 0.f, a2 = 0.f;
        for (int k = 0; k < HID; ++k) {
            float iv = hist[b * HID + k];
            a1 += iv * W[(long)k * HID + tid];
            a2 += iv * W[(long)k * HID + tid + 256];
        }
        o[b * HID + tid] = a1;
        o[b * HID + tid + 256] = a2;
    }
}

// bf16 per-b 512x512 transpose: tkT[b][h][t] = tk[b][t][h]
__global__ void trans_tk(const short* __restrict__ tk, short* __restrict__ tkT) {
    __shared__ short t[32][33];
    const short* src = tk + (long)blockIdx.z * 262144;
    short* dst = tkT + (long)blockIdx.z * 262144;
    int t0 = blockIdx.y * 32, h0 = blockIdx.x * 32;
    int tx = threadIdx.x & 31, ty = threadIdx.x >> 5;
#pragma unroll
    for (int i = 0; i < 32; i += 8)
        t[ty + i][tx] = src[(long)(t0 + ty + i) * 512 + h0 + tx];
    __syncthreads();
#pragma unroll
    for (int i = 0; i < 32; i += 8)
        dst[(long)(h0 + ty + i) * 512 + t0 + tx] = t[tx][ty + i];
}

// tq_bf16[b, s*64+h, :] = bf16(elu(qd[b,s] + qh[b] + qe[b,h] + b_tq))
__global__ void build_tq(const float* __restrict__ qdhq, const float* __restrict__ qh,
                         const float* __restrict__ qe, const float* __restrict__ b_tq,
                         short* __restrict__ tqb)
{
    long gid = (long)blockIdx.x * 256 + threadIdx.x;
    int r = (int)(gid >> 7), j0 = ((int)gid & 127) * 4;
    int b = r >> 11, rem = r & 2047, s = rem >> 6, h = rem & 63;
    float4 d = *(const float4*)(qdhq + (long)(b * 32 + s) * 1024 + j0);
    float4 q = *(const float4*)(qh + (long)b * 512 + j0);
    float4 e = *(const float4*)(qe + (long)(b * 64 + h) * 512 + j0);
    float4 bb = *(const float4*)(b_tq + j0);
    short4 o;
    o.x = f2bs(eluf(d.x + q.x + e.x + bb.x));
    o.y = f2bs(eluf(d.y + q.y + e.y + bb.y));
    o.z = f2bs(eluf(d.z + q.z + e.z + bb.z));
    o.w = f2bs(eluf(d.w + q.w + e.w + bb.w));
    *(short4*)(tqb + (long)r * 512 + j0) = o;
}

// mask + row softmax over 512: bf16 scores in -> bf16 P out. 4 rows / block.
__global__ __launch_bounds__(256) void sm_kernel(
    const short* __restrict__ sc, const int* __restrict__ adj, const int* __restrict__ dup,
    short* __restrict__ Pb)
{
    int w = threadIdx.x >> 6, lane = threadIdx.x & 63;
    long r = (long)blockIdx.x * 4 + w;
    int b = (int)(r >> 11), rem = (int)(r & 2047), s = rem >> 6, h = rem & 63;
    const short* row = sc + r * 512;
    const int* adjr = adj + ((long)(b * 64 + h)) * 512;
    const int* dupr = dup + ((long)(b * 32 + s)) * 512;
    float v[8];
    float m = -INFINITY;
#pragma unroll
    for (int i = 0; i < 8; ++i) {
        int t = lane + 64 * i;
        bool ok = adjr[t] && !dupr[t];
        v[i] = ok ? b2f(row[t]) : -INFINITY;
        m = fmaxf(m, v[i]);
    }
#pragma unroll
    for (int d = 32; d >= 1; d >>= 1) m = fmaxf(m, __shfl_xor(m, d));
    float sum = 0.f;
#pragma unroll
    for (int i = 0; i < 8; ++i) {
        float e = (m == -INFINITY) ? 0.f : expf(v[i] - m);
        v[i] = e; sum += e;
    }
#pragma unroll
    for (int d = 32; d >= 1; d >>= 1) sum += __shfl_xor(sum, d);
    float inv = sum > 0.f ? 1.f / sum : 0.f;
#pragma unroll
    for (int i = 0; i < 8; ++i)
        Pb[r * 512 + lane + 64 * i] = f2bs(v[i] * inv);
}

// hq build + hscores + head softmax + prob + log, one block per n (=b*32+s)
__global__ __launch_bounds__(256) void fused_head(
    const float* __restrict__ qdhq, const float* __restrict__ hq2, const float* __restrict__ b_hq,
    const short* __restrict__ hk, const int* __restrict__ head,
    const short* __restrict__ ta, float* __restrict__ out)
{
    int n = blockIdx.x, b = n >> 5;
    int tid = threadIdx.x;
    __shared__ float hql[512];
    __shared__ float hsl[64];
    __shared__ float hal[64];

    for (int j = tid; j < 512; j += 256)
        hql[j] = eluf(qdhq[(long)n * 1024 + 512 + j] + hq2[b * 512 + j] + b_hq[j]);
    __syncthreads();

    {   // hscores: 4 threads per k
        int k = tid >> 2, p = tid & 3;
        const short* hkr = hk + ((long)n * 64 + k) * 512 + p * 128;
        const float* hq0 = hql + p * 128;
        float a = 0.f;
        for (int j = 0; j < 128; ++j) a += hq0[j] * b2f(hkr[j]);
        a += __shfl_xor(a, 1);
        a += __shfl_xor(a, 2);
        if (p == 0) hsl[k] = a;
    }
    __syncthreads();

    if (tid < 64) {
        int hv = head[b * 64 + tid];
        unsigned long long ball = __ballot(hv != 0);
        int len = __popcll(ball);
        float sv = (tid < len) ? hsl[tid] : -INFINITY;
        float m = sv;
#pragma unroll
        for (int d = 32; d >= 1; d >>= 1) m = fmaxf(m, __shfl_xor(m, d));
        float e = expf(sv - m);
        float sum = e;
#pragma unroll
        for (int d = 32; d >= 1; d >>= 1) sum += __shfl_xor(sum, d);
        hal[tid] = e / sum;
    }
    __syncthreads();

    const short* tab = ta + (long)n * 64 * 512;
#pragma unroll 2
    for (int t = tid; t < 512; t += 256) {
        float a = 0.f;
        for (int k = 0; k < 64; ++k) a += hal[k] * b2f(tab[(long)k * 512 + t]);
        out[(long)n * 512 + t] = logf(a + 1e-20f);
    }
}

extern "C" void kernel_launch(void* const* d_in, const int* in_sizes, int n_in,
                              void* d_out, int out_size, void* d_ws, size_t ws_size,
                              hipStream_t stream)
{
    const float* dec_out = (const float*)d_in[0];
    const float* history = (const float*)d_in[1];
    const int*   head    = (const int*)d_in[2];
    const int*   tail    = (const int*)d_in[3];
    const int*   adj     = (const int*)d_in[4];
    const int*   dup     = (const int*)d_in[5];
    const float* emb     = (const float*)d_in[6];
    const float* W_tq    = (const float*)d_in[7];
    const float* b_tq    = (const float*)d_in[8];
    const float* W_tk    = (const float*)d_in[9];
    const float* b_tk    = (const float*)d_in[10];
    const float* W_tout  = (const float*)d_in[11];
    const float* W_hq    = (const float*)d_in[12];
    const float* b_hq    = (const float*)d_in[13];
    const float* W_hk    = (const float*)d_in[14];
    const float* b_hk    = (const float*)d_in[15];
    float* out = (float*)d_out;

    char* ws = (char*)d_ws;
    auto alloc = [&](size_t bytes) -> void* {
        char* p = ws;
        ws += (bytes + 255) & ~(size_t)255;
        return (void*)p;
    };
    short* decb   = (short*)alloc(131072 * 2);
    short* embAll = (short*)alloc((size_t)4608 * 512 * 2);   // head rows 0..511, tail 512..4607
    short* WT     = (short*)alloc((size_t)7 * 512 * 512 * 2);
    float* qh     = (float*)alloc(8 * 512 * 4);
    float* hq2    = (float*)alloc(8 * 512 * 4);
    float* qdhq   = (float*)alloc((size_t)256 * 1024 * 4);
    float* qe     = (float*)alloc((size_t)512 * 512 * 4);
    short* tkb    = (short*)alloc((size_t)4096 * 512 * 2);
    short* tkTb   = (short*)alloc((size_t)4096 * 512 * 2);
    short* tqb    = (short*)alloc((size_t)16384 * 512 * 2);
    short* scb    = (short*)alloc((size_t)16384 * 512 * 2);  // raw scores; reused as gh
    short* Pb     = (short*)alloc((size_t)16384 * 512 * 2);  // tail_attn bf16 (lives to the end)
    short* ctxb   = (short*)alloc((size_t)16384 * 512 * 2);  // ctx; reused as hk
    short* ghb = scb;
    short* hkb = ctxb;

    short* WT0 = WT;                           // W_tq[:512]^T  (+W_hq[:512]^T at +1)
    short* WT2 = WT + (size_t)2 * 262144;      // W_tq[1024:]^T
    short* WT3 = WT + (size_t)3 * 262144;      // W_tk^T
    short* WT4 = WT + (size_t)4 * 262144;      // W_tout[:512]^T
    short* WT5 = WT + (size_t)5 * 262144;      // W_tout[512:]^T
    short* WT6 = WT + (size_t)6 * 262144;      // W_hk^T

    WTDesc wd;
    wd.src[0] = W_tq;               wd.dst[0] = WT0;
    wd.src[1] = W_hq;               wd.dst[1] = WT + 262144;
    wd.src[2] = W_tq + 1024 * 512;  wd.dst[2] = WT2;
    wd.src[3] = W_tk;               wd.dst[3] = WT3;
    wd.src[4] = W_tout;             wd.dst[4] = WT4;
    wd.src[5] = W_tout + 512 * 512; wd.dst[5] = WT5;
    wd.src[6] = W_hk;               wd.dst[6] = WT6;
    wd.src[7] = W_tk;               wd.dst[7] = WT3;  // unused

    // 1: all casts / transposes / matvecs
    prep<<<6928, 256, 0, stream>>>(dec_out, decb, emb, head, tail, embAll, wd,
                                   history, W_tq + 512 * 512, W_hq + 512 * 512, qh, hq2);
    // 2: qdhq | qe | tk in one launch
    mgemm_multi<<<160, 256, 0, stream>>>(decb, WT0, qdhq, embAll, WT2, qe, WT3, b_tk, tkb);
    // 3: tkT for the PV GEMM
    trans_tk<<<dim3(16, 16, 8), 256, 0, stream>>>(tkb, tkTb);
    // 4: tq bf16
    build_tq<<<8192, 256, 0, stream>>>(qdhq, qh, qe, b_tq, tqb);
    // 5: raw scores bf16 (mask deferred to softmax)
    mgemm<0, 1, 0><<<dim3(4, 16, 8), 256, 0, stream>>>(
        tqb, (long)2048 * 512, tkb, 262144, nullptr, nullptr, nullptr, scb, (long)2048 * 512, 512, 512);
    // 6: mask + softmax -> P bf16
    sm_kernel<<<4096, 256, 0, stream>>>(scb, adj, dup, Pb);
    // 7: ctx = P @ tkT^T
    mgemm<0, 1, 0><<<dim3(4, 16, 8), 256, 0, stream>>>(
        Pb, (long)2048 * 512, tkTb, 262144, nullptr, nullptr, nullptr, ctxb, (long)2048 * 512, 512, 512);
    // 8: gh = tanh(ctx@WT4^T + tq@WT5^T)  (writes over scb)
    mgemm<2, 1, 1><<<dim3(4, 128, 1), 256, 0, stream>>>(
        ctxb, 0, WT4, 0, tqb, WT5, nullptr, ghb, 0, 512, 512);
    // 9: hk = elu(gh@WT6^T + b_hk)  (writes over ctxb)
    mgemm<1, 1, 0><<<dim3(4, 128, 1), 256, 0, stream>>>(
        ghb, 0, WT6, 0, nullptr, nullptr, b_hk, hkb, 0, 512, 512);
    // 10: head attention + prob + log
    fused_head<<<256, 256, 0, stream>>>(qdhq, hq2, b_hq, hkb, head, Pb, out);
}

// Round 4
// 237.109 us; speedup vs baseline: 4.9006x; 1.2919x over previous
//
#include <hip/hip_runtime.h>
#include <math.h>

#define BB 8
#define SS 32
#define HN 64
#define TN 512
#define HID 512

typedef __attribute__((ext_vector_type(8))) short short8;
typedef __attribute__((ext_vector_type(4))) float f32x4;

__device__ __forceinline__ float eluf(float x) { return x > 0.f ? x : (expf(x) - 1.f); }

__device__ __forceinline__ short f2bs(float f) {
    union { float f; unsigned int u; } v; v.f = f;
    unsigned int r = v.u + 0x7fffu + ((v.u >> 16) & 1u);
    return (short)(r >> 16);
}
__device__ __forceinline__ float b2f(short s) {
    union { unsigned int u; float f; } v;
    v.u = ((unsigned int)(unsigned short)s) << 16;
    return v.f;
}

__device__ __forceinline__ void gld16(const void* g, void* l) {
    __builtin_amdgcn_global_load_lds(
        (const __attribute__((address_space(1))) void*)g,
        (__attribute__((address_space(3))) void*)l, 16, 0, 0);
}

// ---------------------------------------------------------------------------
// GEMM core: C[128x128 tile] = act(A@B^T (+A2@B2^T) + bias), bf16 in, MFMA.
// Ls = 8192 shorts (16KB): staging [Al | Bl], reused as epilogue buffer.
// Epilogue (OUTB=1): fragment -> per-wave LDS (16x72 bf16) -> dwordx4 stores.
// ---------------------------------------------------------------------------
template <int ACT, int OUTB, int DUAL>
__device__ __forceinline__ void gcore(
    const short* __restrict__ A, const short* __restrict__ B,
    const short* __restrict__ A2, const short* __restrict__ B2,
    const float* __restrict__ bias, void* __restrict__ Cv,
    int ldc, int K, int m0, int n0, int cm0, short* Ls)
{
    short* Al = Ls;
    short* Bl = Ls + 4096;
    const int tid  = threadIdx.x;
    const int lane = tid & 63;
    const int w    = tid >> 6;
    const int wr   = w >> 1, wc = w & 1;
    const int l16  = lane & 15, quad = lane >> 4;

    const int srow = w * 16 + (lane >> 2);
    const int scol = (lane & 3) * 8;

    f32x4 acc[4][4];
#pragma unroll
    for (int i = 0; i < 4; ++i)
#pragma unroll
        for (int j = 0; j < 4; ++j) { acc[i][j][0]=0.f; acc[i][j][1]=0.f; acc[i][j][2]=0.f; acc[i][j][3]=0.f; }

    short* lA = Al + w * 512;
    short* lB = Bl + w * 512;
    const long rstep = (long)64 * K;

    for (int rep = 0; rep <= DUAL; ++rep) {
        const short* Ag = (rep ? A2 : A) + (long)(m0 + srow) * K + scol;
        const short* Bg = (rep ? B2 : B) + (long)(n0 + srow) * K + scol;
        for (int kt = 0; kt < K; kt += 32) {
            __syncthreads();
            gld16(Ag + kt, lA);
            gld16(Ag + kt + rstep, lA + 2048);
            gld16(Bg + kt, lB);
            gld16(Bg + kt + rstep, lB + 2048);
            __syncthreads();
            short8 af[4], bf4[4];
#pragma unroll
            for (int mi = 0; mi < 4; ++mi)
                af[mi] = *(const short8*)(Al + (wr * 64 + mi * 16 + l16) * 32 + quad * 8);
#pragma unroll
            for (int ni = 0; ni < 4; ++ni)
                bf4[ni] = *(const short8*)(Bl + (wc * 64 + ni * 16 + l16) * 32 + quad * 8);
#pragma unroll
            for (int mi = 0; mi < 4; ++mi)
#pragma unroll
                for (int ni = 0; ni < 4; ++ni)
                    acc[mi][ni] = __builtin_amdgcn_mfma_f32_16x16x32_bf16(af[mi], bf4[ni], acc[mi][ni], 0, 0, 0);
        }
    }

    __syncthreads();   // staging LDS now dead; safe to reuse for epilogue

    float bv[4];
#pragma unroll
    for (int ni = 0; ni < 4; ++ni)
        bv[ni] = bias ? bias[n0 + wc * 64 + ni * 16 + l16] : 0.f;

    if (OUTB) {
        short* eb = Ls + w * 1152;                 // 16 rows x 72-short stride
        const int er = lane >> 2;
        const int ec = (lane & 3) * 16;
#pragma unroll
        for (int mi = 0; mi < 4; ++mi) {
#pragma unroll
            for (int ni = 0; ni < 4; ++ni)
#pragma unroll
                for (int r = 0; r < 4; ++r) {
                    float x = acc[mi][ni][r] + bv[ni];
                    if (ACT == 1) x = eluf(x);
                    else if (ACT == 2) x = tanhf(x);
                    eb[(quad * 4 + r) * 72 + ni * 16 + l16] = f2bs(x);
                }
            __builtin_amdgcn_sched_barrier(0);     // wave-sync LDS idiom: no reorder
            short8 v0 = *(const short8*)&eb[er * 72 + ec];
            short8 v1 = *(const short8*)&eb[er * 72 + ec + 8];
            long cb = (long)(cm0 + wr * 64 + mi * 16 + er) * ldc + n0 + wc * 64 + ec;
            *(short8*)((short*)Cv + cb)     = v0;
            *(short8*)((short*)Cv + cb + 8) = v1;
            __builtin_amdgcn_sched_barrier(0);     // don't overwrite before stores read
        }
    } else {
#pragma unroll
        for (int mi = 0; mi < 4; ++mi)
#pragma unroll
            for (int ni = 0; ni < 4; ++ni) {
                int gc = n0 + wc * 64 + ni * 16 + l16;
#pragma unroll
                for (int r = 0; r < 4; ++r) {
                    float x = acc[mi][ni][r] + bv[ni];
                    if (ACT == 1) x = eluf(x);
                    else if (ACT == 2) x = tanhf(x);
                    ((float*)Cv)[(long)(cm0 + wr * 64 + mi * 16 + quad * 4 + r) * ldc + gc] = x;
                }
            }
    }
}

template <int ACT, int OUTB, int DUAL>
__global__ __launch_bounds__(256) void mgemm(
    const short* __restrict__ A, long sAz,
    const short* __restrict__ B, long sBz,
    const short* __restrict__ A2, long sA2z,
    const short* __restrict__ B2,
    const float* __restrict__ bias,
    void* __restrict__ Cv, long sCz, int ldc, int K)
{
    __shared__ short Ls[8192];
    const int z = blockIdx.z;
    void* C = OUTB ? (void*)((short*)Cv + (long)z * sCz) : (void*)((float*)Cv + (long)z * sCz);
    const short* A2z = DUAL ? (A2 + (long)z * sA2z) : nullptr;
    gcore<ACT, OUTB, DUAL>(A + (long)z * sAz, B + (long)z * sBz, A2z, B2, bias, C,
                           ldc, K, blockIdx.y * 128, blockIdx.x * 128, blockIdx.y * 128, Ls);
}

// qall (48) | qe (16) | tk (128) in one launch
__global__ __launch_bounds__(256) void mgemm_multi(
    const short* __restrict__ decb, const short* __restrict__ WTall, float* __restrict__ qall,
    const short* __restrict__ embAll, const short* __restrict__ WTe, float* __restrict__ qe,
    const short* __restrict__ WTk, const float* __restrict__ b_tk, short* __restrict__ tkb)
{
    __shared__ short Ls[8192];
    int id = blockIdx.x;
    if (id < 48) {                 // qall = [dec;hist] @ [Wd;Whq1;Wtq2;Whq2]^T, fp32
        int y = id >> 4, x = id & 15;
        gcore<0, 0, 0>(decb, WTall, nullptr, nullptr, nullptr, qall, 2048, 512,
                       y * 128, x * 128, y * 128, Ls);
    } else if (id < 64) {          // qe = headEmb @ We^T, fp32
        int id2 = id - 48, y = id2 >> 2, x = id2 & 3;
        gcore<0, 0, 0>(embAll, WTe, nullptr, nullptr, nullptr, qe, 512, 512,
                       y * 128, x * 128, y * 128, Ls);
    } else {                       // tk = elu(tailEmb @ Wtk^T + b_tk), bf16
        int id3 = id - 64, y = id3 >> 2, x = id3 & 3;
        gcore<1, 1, 0>(embAll, WTk, nullptr, nullptr, b_tk, tkb, 512, 512,
                       512 + y * 128, x * 128, y * 128, Ls);
    }
}

// ---------------------------------------------------------------------------
// prep: cast dec+hist | gather+cast emb rows | transpose-cast 9 weights
// ---------------------------------------------------------------------------
struct WTDesc { const float* src[9]; short* dst[9]; };

__global__ __launch_bounds__(256) void prep(
    const float* __restrict__ dec_out, const float* __restrict__ history,
    short* __restrict__ decb,
    const float* __restrict__ emb, const int* __restrict__ head, const int* __restrict__ tail,
    short* __restrict__ embAll, WTDesc wd)
{
    __shared__ float t[32][33];
    const int id = blockIdx.x, tid = threadIdx.x;
    if (id < 528) {                        // dec (131072) + hist (4096) casts
        int i = id * 256 + tid;
        float v = (i < 131072) ? dec_out[i] : history[i - 131072];
        decb[i] = f2bs(v);
    } else if (id < 528 + 4608) {          // gather+cast emb rows (head|tail)
        int r = id - 528;
        int idx = (r < 512) ? head[r] : tail[r - 512];
        const float* s = emb + (long)idx * 512;
        short* dst = embAll + (long)r * 512;
        dst[tid]       = f2bs(s[tid]);
        dst[tid + 256] = f2bs(s[tid + 256]);
    } else {                               // transpose-cast 9 weight matrices
        int q = id - 5136;
        int z = q >> 8, xy = q & 255;
        int x = xy & 15, y = xy >> 4;
        const float* src = wd.src[z];
        short* dst = wd.dst[z];
        int k0 = y * 32, n0 = x * 32;
        int tx = tid & 31, ty = tid >> 5;
#pragma unroll
        for (int i = 0; i < 32; i += 8)
            t[ty + i][tx] = src[(long)(k0 + ty + i) * 512 + n0 + tx];
        __syncthreads();
#pragma unroll
        for (int i = 0; i < 32; i += 8)
            dst[(long)(n0 + ty + i) * 512 + k0 + tx] = f2bs(t[tx][ty + i]);
    }
}

// ---------------------------------------------------------------------------
// L3: build_tq (8192 blocks) | tkWT GEMM (128 blocks)
// ---------------------------------------------------------------------------
__global__ __launch_bounds__(256) void l3_kernel(
    const float* __restrict__ qall, const float* __restrict__ qe,
    const float* __restrict__ b_tq, short* __restrict__ tqb,
    const short* __restrict__ WTo1, const short* __restrict__ tkb, short* __restrict__ tkWTb)
{
    __shared__ short Ls[8192];
    if (blockIdx.x < 8192) {
        long gid = (long)blockIdx.x * 256 + threadIdx.x;
        int r = (int)(gid >> 7), j0 = ((int)gid & 127) * 4;
        int b = r >> 11, rem = r & 2047, s = rem >> 6, h = rem & 63;
        float4 d = *(const float4*)(qall + (long)(b * 32 + s) * 2048 + j0);
        float4 q = *(const float4*)(qall + (long)(256 + b) * 2048 + 1024 + j0);
        float4 e = *(const float4*)(qe + (long)(b * 64 + h) * 512 + j0);
        float4 bb = *(const float4*)(b_tq + j0);
        short4 o;
        o.x = f2bs(eluf(d.x + q.x + e.x + bb.x));
        o.y = f2bs(eluf(d.y + q.y + e.y + bb.y));
        o.z = f2bs(eluf(d.z + q.z + e.z + bb.z));
        o.w = f2bs(eluf(d.w + q.w + e.w + bb.w));
        *(short4*)(tqb + (long)r * 512 + j0) = o;
    } else {
        // tkWT[b][n][t] = sum_h W_tout1[h][n] * tk[b][t][h]
        int id2 = blockIdx.x - 8192;       // 0..127
        int z = id2 >> 4, r = id2 & 15;
        int x = r & 3, y = r >> 2;
        gcore<0, 1, 0>(WTo1, tkb + (long)z * 262144, nullptr, nullptr, nullptr,
                       tkWTb + (long)z * 262144, 512, 512, y * 128, x * 128, y * 128, Ls);
    }
}

// mask + row softmax over 512: bf16 scores -> bf16 P. 4 rows/block, short8 loads.
__global__ __launch_bounds__(256) void sm_kernel(
    const short* __restrict__ sc, const int* __restrict__ adj, const int* __restrict__ dup,
    short* __restrict__ Pb)
{
    int w = threadIdx.x >> 6, lane = threadIdx.x & 63;
    long r = (long)blockIdx.x * 4 + w;
    int b = (int)(r >> 11), rem = (int)(r & 2047), s = rem >> 6, h = rem & 63;
    const short* row = sc + r * 512 + lane * 8;
    const int* adjr = adj + ((long)(b * 64 + h)) * 512 + lane * 8;
    const int* dupr = dup + ((long)(b * 32 + s)) * 512 + lane * 8;
    short8 v8 = *(const short8*)row;
    int4 a0 = *(const int4*)adjr, a1 = *(const int4*)(adjr + 4);
    int4 d0 = *(const int4*)dupr, d1 = *(const int4*)(dupr + 4);
    int am[8] = {a0.x, a0.y, a0.z, a0.w, a1.x, a1.y, a1.z, a1.w};
    int dm[8] = {d0.x, d0.y, d0.z, d0.w, d1.x, d1.y, d1.z, d1.w};
    float v[8];
    float m = -INFINITY;
#pragma unroll
    for (int i = 0; i < 8; ++i) {
        v[i] = (am[i] && !dm[i]) ? b2f(v8[i]) : -INFINITY;
        m = fmaxf(m, v[i]);
    }
#pragma unroll
    for (int d = 32; d >= 1; d >>= 1) m = fmaxf(m, __shfl_xor(m, d));
    float sum = 0.f;
#pragma unroll
    for (int i = 0; i < 8; ++i) {
        float e = (m == -INFINITY) ? 0.f : expf(v[i] - m);
        v[i] = e; sum += e;
    }
#pragma unroll
    for (int d = 32; d >= 1; d >>= 1) sum += __shfl_xor(sum, d);
    float inv = sum > 0.f ? 1.f / sum : 0.f;
    short8 o;
#pragma unroll
    for (int i = 0; i < 8; ++i) o[i] = f2bs(v[i] * inv);
    *(short8*)(Pb + r * 512 + lane * 8) = o;
}

// hq build + hscores + head softmax + prob + log; one block per n
__global__ __launch_bounds__(256) void fused_head(
    const float* __restrict__ qall, const float* __restrict__ b_hq,
    const short* __restrict__ hk, const int* __restrict__ head,
    const short* __restrict__ ta, float* __restrict__ out)
{
    int n = blockIdx.x, b = n >> 5;
    int tid = threadIdx.x;
    __shared__ float hql[512];
    __shared__ float hsl[64];
    __shared__ float hal[64];
    __shared__ float part[4][512];

    for (int j = tid; j < 512; j += 256)
        hql[j] = eluf(qall[(long)n * 2048 + 512 + j] + qall[(long)(256 + b) * 2048 + 1536 + j] + b_hq[j]);
    __syncthreads();

    {   // hscores: 4 threads per k, short8 loads
        int k = tid >> 2, p = tid & 3;
        const short* hkr = hk + ((long)n * 64 + k) * 512 + p * 128;
        const float* hq0 = hql + p * 128;
        float a = 0.f;
#pragma unroll 4
        for (int jj = 0; jj < 128; jj += 8) {
            short8 hv = *(const short8*)(hkr + jj);
#pragma unroll
            for (int u = 0; u < 8; ++u) a += b2f(hv[u]) * hq0[jj + u];
        }
        a += __shfl_xor(a, 1);
        a += __shfl_xor(a, 2);
        if (p == 0) hsl[k] = a;
    }
    __syncthreads();

    if (tid < 64) {
        int hv = head[b * 64 + tid];
        unsigned long long ball = __ballot(hv != 0);
        int len = __popcll(ball);
        float sv = (tid < len) ? hsl[tid] : -INFINITY;
        float m = sv;
#pragma unroll
        for (int d = 32; d >= 1; d >>= 1) m = fmaxf(m, __shfl_xor(m, d));
        float e = expf(sv - m);
        float sum = e;
#pragma unroll
        for (int d = 32; d >= 1; d >>= 1) sum += __shfl_xor(sum, d);
        hal[tid] = e / sum;
    }
    __syncthreads();

    {   // prob partials: wave w covers k = w*16..w*16+16, lane owns 8 t's
        int w = tid >> 6, lane = tid & 63;
        const short* tab = ta + (long)n * 64 * 512 + (long)(w * 16) * 512 + lane * 8;
        float acc[8] = {};
#pragma unroll
        for (int k = 0; k < 16; ++k) {
            float a = hal[w * 16 + k];
            short8 tv = *(const short8*)(tab + (long)k * 512);
#pragma unroll
            for (int u = 0; u < 8; ++u) acc[u] += a * b2f(tv[u]);
        }
        float4* pp = (float4*)&part[w][lane * 8];
        pp[0] = make_float4(acc[0], acc[1], acc[2], acc[3]);
        pp[1] = make_float4(acc[4], acc[5], acc[6], acc[7]);
    }
    __syncthreads();

    for (int t = tid; t < 512; t += 256) {
        float a = part[0][t] + part[1][t] + part[2][t] + part[3][t];
        out[(long)n * 512 + t] = logf(a + 1e-20f);
    }
}

extern "C" void kernel_launch(void* const* d_in, const int* in_sizes, int n_in,
                              void* d_out, int out_size, void* d_ws, size_t ws_size,
                              hipStream_t stream)
{
    const float* dec_out = (const float*)d_in[0];
    const float* history = (const float*)d_in[1];
    const int*   head    = (const int*)d_in[2];
    const int*   tail    = (const int*)d_in[3];
    const int*   adj     = (const int*)d_in[4];
    const int*   dup     = (const int*)d_in[5];
    const float* emb     = (const float*)d_in[6];
    const float* W_tq    = (const float*)d_in[7];
    const float* b_tq    = (const float*)d_in[8];
    const float* W_tk    = (const float*)d_in[9];
    const float* b_tk    = (const float*)d_in[10];
    const float* W_tout  = (const float*)d_in[11];
    const float* W_hq    = (const float*)d_in[12];
    const float* b_hq    = (const float*)d_in[13];
    const float* W_hk    = (const float*)d_in[14];
    const float* b_hk    = (const float*)d_in[15];
    float* out = (float*)d_out;

    char* ws = (char*)d_ws;
    auto alloc = [&](size_t bytes) -> void* {
        char* p = ws;
        ws += (bytes + 255) & ~(size_t)255;
        return (void*)p;
    };
    short* decb   = (short*)alloc((size_t)384 * 512 * 2);    // dec 0..255, hist 256..263
    short* embAll = (short*)alloc((size_t)4608 * 512 * 2);   // head 0..511, tail 512..4607
    short* WT     = (short*)alloc((size_t)9 * 512 * 512 * 2);
    float* qall   = (float*)alloc((size_t)384 * 2048 * 4);   // [qd|hqp|qh'|hq2']
    float* qe     = (float*)alloc((size_t)512 * 512 * 4);
    short* tkb    = (short*)alloc((size_t)4096 * 512 * 2);
    short* tkWTb  = (short*)alloc((size_t)4096 * 512 * 2);
    short* tqb    = (short*)alloc((size_t)16384 * 512 * 2);
    short* scb    = (short*)alloc((size_t)16384 * 512 * 2);  // scores -> gh
    short* Pb     = (short*)alloc((size_t)16384 * 512 * 2);  // tail_attn (to the end)
    short* ghb = scb;   // scores dead after sm
    short* hkb = tqb;   // tq dead after gh

    // WT slab: 0 Wd^T | 1 Whq1^T | 2 Wtq2^T | 3 Whq2^T | 4 We^T | 5 Wtk^T
    //          6 Wtout1^T | 7 Wtout2^T | 8 Whk^T
    WTDesc wd;
    wd.src[0] = W_tq;               wd.dst[0] = WT;
    wd.src[1] = W_hq;               wd.dst[1] = WT + (size_t)1 * 262144;
    wd.src[2] = W_tq + 512 * 512;   wd.dst[2] = WT + (size_t)2 * 262144;
    wd.src[3] = W_hq + 512 * 512;   wd.dst[3] = WT + (size_t)3 * 262144;
    wd.src[4] = W_tq + 1024 * 512;  wd.dst[4] = WT + (size_t)4 * 262144;
    wd.src[5] = W_tk;               wd.dst[5] = WT + (size_t)5 * 262144;
    wd.src[6] = W_tout;             wd.dst[6] = WT + (size_t)6 * 262144;
    wd.src[7] = W_tout + 512 * 512; wd.dst[7] = WT + (size_t)7 * 262144;
    wd.src[8] = W_hk;               wd.dst[8] = WT + (size_t)8 * 262144;

    // 1: casts / gathers / weight transposes
    prep<<<7440, 256, 0, stream>>>(dec_out, history, decb, emb, head, tail, embAll, wd);
    // 2: qall | qe | tk
    mgemm_multi<<<192, 256, 0, stream>>>(decb, WT, qall, embAll, WT + (size_t)4 * 262144, qe,
                                         WT + (size_t)5 * 262144, b_tk, tkb);
    // 3: build tq | tkWT = Wtout1^T @ tk^T (per b)
    l3_kernel<<<8320, 256, 0, stream>>>(qall, qe, b_tq, tqb, WT + (size_t)6 * 262144, tkb, tkWTb);
    // 4: raw scores = tq @ tk^T (per b), bf16
    mgemm<0, 1, 0><<<dim3(4, 16, 8), 256, 0, stream>>>(
        tqb, (long)2048 * 512, tkb, 262144, nullptr, 0, nullptr, nullptr,
        scb, (long)2048 * 512, 512, 512);
    // 5: mask + softmax -> P
    sm_kernel<<<4096, 256, 0, stream>>>(scb, adj, dup, Pb);
    // 6: gh = tanh(P @ tkWT^T + tq @ Wtout2^T)   (writes over scb)
    mgemm<2, 1, 1><<<dim3(4, 16, 8), 256, 0, stream>>>(
        Pb, (long)2048 * 512, tkWTb, 262144, tqb, (long)2048 * 512, WT + (size_t)7 * 262144,
        nullptr, ghb, (long)2048 * 512, 512, 512);
    // 7: hk = elu(gh @ Whk^T + b_hk)   (writes over tqb)
    mgemm<1, 1, 0><<<dim3(4, 128, 1), 256, 0, stream>>>(
        ghb, 0, WT + (size_t)8 * 262144, 0, nullptr, 0, nullptr, b_hk,
        hkb, 0, 512, 512);
    // 8: head attention + prob + log
    fused_head<<<256, 256, 0, stream>>>(qall, b_hq, hkb, head, Pb, out);
}

// Round 5
// 224.365 us; speedup vs baseline: 5.1790x; 1.0568x over previous
//
#include <hip/hip_runtime.h>
#include <math.h>

#define BB 8
#define SS 32
#define HN 64
#define TN 512
#define HID 512

typedef __attribute__((ext_vector_type(8))) short short8;
typedef __attribute__((ext_vector_type(4))) float f32x4;

__device__ __forceinline__ float eluf(float x) { return x > 0.f ? x : (expf(x) - 1.f); }

__device__ __forceinline__ short f2bs(float f) {
    union { float f; unsigned int u; } v; v.f = f;
    unsigned int r = v.u + 0x7fffu + ((v.u >> 16) & 1u);
    return (short)(r >> 16);
}
__device__ __forceinline__ float b2f(short s) {
    union { unsigned int u; float f; } v;
    v.u = ((unsigned int)(unsigned short)s) << 16;
    return v.f;
}

__device__ __forceinline__ void gld16(const void* g, void* l) {
    __builtin_amdgcn_global_load_lds(
        (const __attribute__((address_space(1))) void*)g,
        (__attribute__((address_space(3))) void*)l, 16, 0, 0);
}

// ---------------------------------------------------------------------------
// GEMM core: C[128x128 tile] = act(A@B^T (+A2@B2^T) + bias), bf16 in, MFMA.
// BK=64: two 128x32 stagings per barrier pair (half the barrier drains of BK=32).
// Ls = 16384 shorts (32KB): staging [A(8K) | B(8K)], reused by epilogues.
// OUTB: 0 = f32 C, 1 = bf16 C via LDS-vectorized dwordx4 stores,
//       2 = hs-mode: no C; per-row dot with hq -> hsp[n0/128][row] partials.
// ---------------------------------------------------------------------------
template <int ACT, int OUTB, int DUAL>
__device__ __forceinline__ void gcore(
    const short* __restrict__ A, const short* __restrict__ B,
    const short* __restrict__ A2, const short* __restrict__ B2,
    const float* __restrict__ bias, void* __restrict__ Cv,
    int ldc, int K, int m0, int n0, int cm0, short* Ls,
    const float* __restrict__ hq, float* __restrict__ hsp)
{
    short* Al = Ls;
    short* Bl = Ls + 8192;
    const int tid  = threadIdx.x;
    const int lane = tid & 63;
    const int w    = tid >> 6;
    const int wr   = w >> 1, wc = w & 1;
    const int l16  = lane & 15, quad = lane >> 4;

    const int srow = w * 16 + (lane >> 2);
    const int scol = (lane & 3) * 8;

    f32x4 acc[4][4];
#pragma unroll
    for (int i = 0; i < 4; ++i)
#pragma unroll
        for (int j = 0; j < 4; ++j) { acc[i][j][0]=0.f; acc[i][j][1]=0.f; acc[i][j][2]=0.f; acc[i][j][3]=0.f; }

    short* lA = Al + w * 512;
    short* lB = Bl + w * 512;
    const long rstep = (long)64 * K;

    for (int rep = 0; rep <= DUAL; ++rep) {
        const short* Ag = (rep ? A2 : A) + (long)(m0 + srow) * K + scol;
        const short* Bg = (rep ? B2 : B) + (long)(n0 + srow) * K + scol;
        for (int kt = 0; kt < K; kt += 64) {
            __syncthreads();
            gld16(Ag + kt, lA);
            gld16(Ag + kt + rstep, lA + 2048);
            gld16(Ag + kt + 32, lA + 4096);
            gld16(Ag + kt + 32 + rstep, lA + 4096 + 2048);
            gld16(Bg + kt, lB);
            gld16(Bg + kt + rstep, lB + 2048);
            gld16(Bg + kt + 32, lB + 4096);
            gld16(Bg + kt + 32 + rstep, lB + 4096 + 2048);
            __syncthreads();
#pragma unroll
            for (int h = 0; h < 2; ++h) {
                short8 af[4], bf4[4];
#pragma unroll
                for (int mi = 0; mi < 4; ++mi)
                    af[mi] = *(const short8*)(Al + h * 4096 + (wr * 64 + mi * 16 + l16) * 32 + quad * 8);
#pragma unroll
                for (int ni = 0; ni < 4; ++ni)
                    bf4[ni] = *(const short8*)(Bl + h * 4096 + (wc * 64 + ni * 16 + l16) * 32 + quad * 8);
#pragma unroll
                for (int mi = 0; mi < 4; ++mi)
#pragma unroll
                    for (int ni = 0; ni < 4; ++ni)
                        acc[mi][ni] = __builtin_amdgcn_mfma_f32_16x16x32_bf16(af[mi], bf4[ni], acc[mi][ni], 0, 0, 0);
            }
        }
    }

    __syncthreads();   // staging LDS dead; safe to reuse for epilogue

    float bv[4];
#pragma unroll
    for (int ni = 0; ni < 4; ++ni)
        bv[ni] = bias ? bias[n0 + wc * 64 + ni * 16 + l16] : 0.f;

    if (OUTB == 1) {
        short* eb = Ls + w * 1152;                 // 16 rows x 72-short stride
        const int er = lane >> 2;
        const int ec = (lane & 3) * 16;
#pragma unroll
        for (int mi = 0; mi < 4; ++mi) {
#pragma unroll
            for (int ni = 0; ni < 4; ++ni)
#pragma unroll
                for (int r = 0; r < 4; ++r) {
                    float x = acc[mi][ni][r] + bv[ni];
                    if (ACT == 1) x = eluf(x);
                    else if (ACT == 2) x = tanhf(x);
                    eb[(quad * 4 + r) * 72 + ni * 16 + l16] = f2bs(x);
                }
            __builtin_amdgcn_sched_barrier(0);     // wave-sync LDS idiom: no reorder
            short8 v0 = *(const short8*)&eb[er * 72 + ec];
            short8 v1 = *(const short8*)&eb[er * 72 + ec + 8];
            long cb = (long)(cm0 + wr * 64 + mi * 16 + er) * ldc + n0 + wc * 64 + ec;
            *(short8*)((short*)Cv + cb)     = v0;
            *(short8*)((short*)Cv + cb + 8) = v1;
            __builtin_amdgcn_sched_barrier(0);     // don't overwrite before stores read
        }
    } else if (OUTB == 2) {
        // hscores partials: wave wr covers rows [cm0+wr*64, +64) = exactly one n
        const int n_w = (cm0 + wr * 64) >> 6;
        float hqv[4];
#pragma unroll
        for (int ni = 0; ni < 4; ++ni)
            hqv[ni] = hq[(long)n_w * 512 + n0 + wc * 64 + ni * 16 + l16];
        float* red = (float*)Ls;                   // [4 waves][64 rows]
#pragma unroll
        for (int mi = 0; mi < 4; ++mi)
#pragma unroll
            for (int r = 0; r < 4; ++r) {
                float p = 0.f;
#pragma unroll
                for (int ni = 0; ni < 4; ++ni) {
                    float x = acc[mi][ni][r] + bv[ni];
                    if (ACT == 1) x = eluf(x);
                    p += x * hqv[ni];
                }
                p += __shfl_xor(p, 1);
                p += __shfl_xor(p, 2);
                p += __shfl_xor(p, 4);
                p += __shfl_xor(p, 8);
                if (l16 == 0) red[w * 64 + mi * 16 + quad * 4 + r] = p;
            }
        __syncthreads();
        if (tid < 128) {
            int wr2 = tid >> 6, rw = tid & 63;
            float v = red[(wr2 * 2 + 0) * 64 + rw] + red[(wr2 * 2 + 1) * 64 + rw];
            hsp[(long)(n0 >> 7) * 16384 + cm0 + tid] = v;
        }
    } else {
#pragma unroll
        for (int mi = 0; mi < 4; ++mi)
#pragma unroll
            for (int ni = 0; ni < 4; ++ni) {
                int gc = n0 + wc * 64 + ni * 16 + l16;
#pragma unroll
                for (int r = 0; r < 4; ++r) {
                    float x = acc[mi][ni][r] + bv[ni];
                    if (ACT == 1) x = eluf(x);
                    else if (ACT == 2) x = tanhf(x);
                    ((float*)Cv)[(long)(cm0 + wr * 64 + mi * 16 + quad * 4 + r) * ldc + gc] = x;
                }
            }
    }
}

template <int ACT, int OUTB, int DUAL>
__global__ __launch_bounds__(256) void mgemm(
    const short* __restrict__ A, long sAz,
    const short* __restrict__ B, long sBz,
    const short* __restrict__ A2, long sA2z,
    const short* __restrict__ B2,
    const float* __restrict__ bias,
    void* __restrict__ Cv, long sCz, int ldc, int K)
{
    __shared__ short Ls[16384];
    const int z = blockIdx.z;
    void* C = OUTB ? (void*)((short*)Cv + (long)z * sCz) : (void*)((float*)Cv + (long)z * sCz);
    const short* A2z = DUAL ? (A2 + (long)z * sA2z) : nullptr;
    gcore<ACT, OUTB, DUAL>(A + (long)z * sAz, B + (long)z * sBz, A2z, B2, bias, C,
                           ldc, K, blockIdx.y * 128, blockIdx.x * 128, blockIdx.y * 128, Ls,
                           nullptr, nullptr);
}

// hs GEMM: rows = gh, cols = Whk^T; epilogue dots with hq -> hsp partials
__global__ __launch_bounds__(256) void mgemm_hs(
    const short* __restrict__ A, const short* __restrict__ B,
    const float* __restrict__ bias, const float* __restrict__ hq, float* __restrict__ hsp)
{
    __shared__ short Ls[16384];
    gcore<1, 2, 0>(A, B, nullptr, nullptr, bias, nullptr, 512, 512,
                   blockIdx.y * 128, blockIdx.x * 128, blockIdx.y * 128, Ls, hq, hsp);
}

// qall (48) | qe (16) | tk (128) in one launch
__global__ __launch_bounds__(256) void mgemm_multi(
    const short* __restrict__ decb, const short* __restrict__ WTall, float* __restrict__ qall,
    const short* __restrict__ embAll, const short* __restrict__ WTe, float* __restrict__ qe,
    const short* __restrict__ WTk, const float* __restrict__ b_tk, short* __restrict__ tkb)
{
    __shared__ short Ls[16384];
    int id = blockIdx.x;
    if (id < 48) {                 // qall = [dec;hist] @ [Wd;Whq1;Wtq2;Whq2]^T, fp32
        int y = id >> 4, x = id & 15;
        gcore<0, 0, 0>(decb, WTall, nullptr, nullptr, nullptr, qall, 2048, 512,
                       y * 128, x * 128, y * 128, Ls, nullptr, nullptr);
    } else if (id < 64) {          // qe = headEmb @ We^T, fp32
        int id2 = id - 48, y = id2 >> 2, x = id2 & 3;
        gcore<0, 0, 0>(embAll, WTe, nullptr, nullptr, nullptr, qe, 512, 512,
                       y * 128, x * 128, y * 128, Ls, nullptr, nullptr);
    } else {                       // tk = elu(tailEmb @ Wtk^T + b_tk), bf16
        int id3 = id - 64, y = id3 >> 2, x = id3 & 3;
        gcore<1, 1, 0>(embAll, WTk, nullptr, nullptr, b_tk, tkb, 512, 512,
                       512 + y * 128, x * 128, y * 128, Ls, nullptr, nullptr);
    }
}

// ---------------------------------------------------------------------------
// prep: cast dec+hist | gather+cast emb rows | transpose-cast 9 weights
// ---------------------------------------------------------------------------
struct WTDesc { const float* src[9]; short* dst[9]; };

__global__ __launch_bounds__(256) void prep(
    const float* __restrict__ dec_out, const float* __restrict__ history,
    short* __restrict__ decb,
    const float* __restrict__ emb, const int* __restrict__ head, const int* __restrict__ tail,
    short* __restrict__ embAll, WTDesc wd)
{
    __shared__ float t[32][33];
    const int id = blockIdx.x, tid = threadIdx.x;
    if (id < 528) {
        int i = id * 256 + tid;
        float v = (i < 131072) ? dec_out[i] : history[i - 131072];
        decb[i] = f2bs(v);
    } else if (id < 528 + 4608) {
        int r = id - 528;
        int idx = (r < 512) ? head[r] : tail[r - 512];
        const float* s = emb + (long)idx * 512;
        short* dst = embAll + (long)r * 512;
        dst[tid]       = f2bs(s[tid]);
        dst[tid + 256] = f2bs(s[tid + 256]);
    } else {
        int q = id - 5136;
        int z = q >> 8, xy = q & 255;
        int x = xy & 15, y = xy >> 4;
        const float* src = wd.src[z];
        short* dst = wd.dst[z];
        int k0 = y * 32, n0 = x * 32;
        int tx = tid & 31, ty = tid >> 5;
#pragma unroll
        for (int i = 0; i < 32; i += 8)
            t[ty + i][tx] = src[(long)(k0 + ty + i) * 512 + n0 + tx];
        __syncthreads();
#pragma unroll
        for (int i = 0; i < 32; i += 8)
            dst[(long)(n0 + ty + i) * 512 + k0 + tx] = f2bs(t[tx][ty + i]);
    }
}

// ---------------------------------------------------------------------------
// L3: build_tq (8192) | tkWT GEMM (128) | hq build (128)
// ---------------------------------------------------------------------------
__global__ __launch_bounds__(256) void l3_kernel(
    const float* __restrict__ qall, const float* __restrict__ qe,
    const float* __restrict__ b_tq, short* __restrict__ tqb,
    const short* __restrict__ WTo1, const short* __restrict__ tkb, short* __restrict__ tkWTb,
    const float* __restrict__ b_hq, float* __restrict__ hqf)
{
    __shared__ short Ls[16384];
    if (blockIdx.x < 8192) {
        long gid = (long)blockIdx.x * 256 + threadIdx.x;
        int r = (int)(gid >> 7), j0 = ((int)gid & 127) * 4;
        int b = r >> 11, rem = r & 2047, s = rem >> 6, h = rem & 63;
        float4 d = *(const float4*)(qall + (long)(b * 32 + s) * 2048 + j0);
        float4 q = *(const float4*)(qall + (long)(256 + b) * 2048 + 1024 + j0);
        float4 e = *(const float4*)(qe + (long)(b * 64 + h) * 512 + j0);
        float4 bb = *(const float4*)(b_tq + j0);
        short4 o;
        o.x = f2bs(eluf(d.x + q.x + e.x + bb.x));
        o.y = f2bs(eluf(d.y + q.y + e.y + bb.y));
        o.z = f2bs(eluf(d.z + q.z + e.z + bb.z));
        o.w = f2bs(eluf(d.w + q.w + e.w + bb.w));
        *(short4*)(tqb + (long)r * 512 + j0) = o;
    } else if (blockIdx.x < 8320) {
        // tkWT[b][n][t] = sum_h W_tout1[h][n] * tk[b][t][h]
        int id2 = blockIdx.x - 8192;       // 0..127
        int z = id2 >> 4, r = id2 & 15;
        int x = r & 3, y = r >> 2;
        gcore<0, 1, 0>(WTo1, tkb + (long)z * 262144, nullptr, nullptr, nullptr,
                       tkWTb + (long)z * 262144, 512, 512, y * 128, x * 128, y * 128, Ls,
                       nullptr, nullptr);
    } else {
        // hq[n][j] = elu(qall[n][512+j] + qall[256+b][1536+j] + b_hq[j]), fp32
        long gid = (long)(blockIdx.x - 8320) * 256 + threadIdx.x;   // 32768 total
        int n = (int)(gid >> 7), j0 = ((int)gid & 127) * 4;
        int b = n >> 5;
        float4 d = *(const float4*)(qall + (long)n * 2048 + 512 + j0);
        float4 h2 = *(const float4*)(qall + (long)(256 + b) * 2048 + 1536 + j0);
        float4 bb = *(const float4*)(b_hq + j0);
        float4 o;
        o.x = eluf(d.x + h2.x + bb.x);
        o.y = eluf(d.y + h2.y + bb.y);
        o.z = eluf(d.z + h2.z + bb.z);
        o.w = eluf(d.w + h2.w + bb.w);
        *(float4*)(hqf + (long)n * 512 + j0) = o;
    }
}

// mask + row softmax over 512: bf16 scores -> bf16 P. 4 rows/block, short8 loads.
__global__ __launch_bounds__(256) void sm_kernel(
    const short* __restrict__ sc, const int* __restrict__ adj, const int* __restrict__ dup,
    short* __restrict__ Pb)
{
    int w = threadIdx.x >> 6, lane = threadIdx.x & 63;
    long r = (long)blockIdx.x * 4 + w;
    int b = (int)(r >> 11), rem = (int)(r & 2047), s = rem >> 6, h = rem & 63;
    const short* row = sc + r * 512 + lane * 8;
    const int* adjr = adj + ((long)(b * 64 + h)) * 512 + lane * 8;
    const int* dupr = dup + ((long)(b * 32 + s)) * 512 + lane * 8;
    short8 v8 = *(const short8*)row;
    int4 a0 = *(const int4*)adjr, a1 = *(const int4*)(adjr + 4);
    int4 d0 = *(const int4*)dupr, d1 = *(const int4*)(dupr + 4);
    int am[8] = {a0.x, a0.y, a0.z, a0.w, a1.x, a1.y, a1.z, a1.w};
    int dm[8] = {d0.x, d0.y, d0.z, d0.w, d1.x, d1.y, d1.z, d1.w};
    float v[8];
    float m = -INFINITY;
#pragma unroll
    for (int i = 0; i < 8; ++i) {
        v[i] = (am[i] && !dm[i]) ? b2f(v8[i]) : -INFINITY;
        m = fmaxf(m, v[i]);
    }
#pragma unroll
    for (int d = 32; d >= 1; d >>= 1) m = fmaxf(m, __shfl_xor(m, d));
    float sum = 0.f;
#pragma unroll
    for (int i = 0; i < 8; ++i) {
        float e = (m == -INFINITY) ? 0.f : expf(v[i] - m);
        v[i] = e; sum += e;
    }
#pragma unroll
    for (int d = 32; d >= 1; d >>= 1) sum += __shfl_xor(sum, d);
    float inv = sum > 0.f ? 1.f / sum : 0.f;
    short8 o;
#pragma unroll
    for (int i = 0; i < 8; ++i) o[i] = f2bs(v[i] * inv);
    *(short8*)(Pb + r * 512 + lane * 8) = o;
}

// head softmax (from hsp partials) + prob + log; one block per n
__global__ __launch_bounds__(256) void fused_head(
    const float* __restrict__ hsp, const int* __restrict__ head,
    const short* __restrict__ ta, float* __restrict__ out)
{
    int n = blockIdx.x, b = n >> 5;
    int tid = threadIdx.x;
    __shared__ float hal[64];
    __shared__ float part[4][512];

    if (tid < 64) {
        float sv_raw = hsp[n * 64 + tid] + hsp[16384 + n * 64 + tid]
                     + hsp[2 * 16384 + n * 64 + tid] + hsp[3 * 16384 + n * 64 + tid];
        int hv = head[b * 64 + tid];
        unsigned long long ball = __ballot(hv != 0);
        int len = __popcll(ball);
        float sv = (tid < len) ? sv_raw : -INFINITY;
        float m = sv;
#pragma unroll
        for (int d = 32; d >= 1; d >>= 1) m = fmaxf(m, __shfl_xor(m, d));
        float e = expf(sv - m);
        float sum = e;
#pragma unroll
        for (int d = 32; d >= 1; d >>= 1) sum += __shfl_xor(sum, d);
        hal[tid] = e / sum;
    }
    __syncthreads();

    {   // prob partials: wave w covers k = w*16..w*16+16, lane owns 8 t's
        int w = tid >> 6, lane = tid & 63;
        const short* tab = ta + (long)n * 64 * 512 + (long)(w * 16) * 512 + lane * 8;
        float acc[8] = {};
#pragma unroll
        for (int k = 0; k < 16; ++k) {
            float a = hal[w * 16 + k];
            short8 tv = *(const short8*)(tab + (long)k * 512);
#pragma unroll
            for (int u = 0; u < 8; ++u) acc[u] += a * b2f(tv[u]);
        }
        float4* pp = (float4*)&part[w][lane * 8];
        pp[0] = make_float4(acc[0], acc[1], acc[2], acc[3]);
        pp[1] = make_float4(acc[4], acc[5], acc[6], acc[7]);
    }
    __syncthreads();

    for (int t = tid; t < 512; t += 256) {
        float a = part[0][t] + part[1][t] + part[2][t] + part[3][t];
        out[(long)n * 512 + t] = logf(a + 1e-20f);
    }
}

extern "C" void kernel_launch(void* const* d_in, const int* in_sizes, int n_in,
                              void* d_out, int out_size, void* d_ws, size_t ws_size,
                              hipStream_t stream)
{
    const float* dec_out = (const float*)d_in[0];
    const float* history = (const float*)d_in[1];
    const int*   head    = (const int*)d_in[2];
    const int*   tail    = (const int*)d_in[3];
    const int*   adj     = (const int*)d_in[4];
    const int*   dup     = (const int*)d_in[5];
    const float* emb     = (const float*)d_in[6];
    const float* W_tq    = (const float*)d_in[7];
    const float* b_tq    = (const float*)d_in[8];
    const float* W_tk    = (const float*)d_in[9];
    const float* b_tk    = (const float*)d_in[10];
    const float* W_tout  = (const float*)d_in[11];
    const float* W_hq    = (const float*)d_in[12];
    const float* b_hq    = (const float*)d_in[13];
    const float* W_hk    = (const float*)d_in[14];
    const float* b_hk    = (const float*)d_in[15];
    float* out = (float*)d_out;

    char* ws = (char*)d_ws;
    auto alloc = [&](size_t bytes) -> void* {
        char* p = ws;
        ws += (bytes + 255) & ~(size_t)255;
        return (void*)p;
    };
    short* decb   = (short*)alloc((size_t)384 * 512 * 2);    // dec 0..255, hist 256..263
    short* embAll = (short*)alloc((size_t)4608 * 512 * 2);   // head 0..511, tail 512..4607
    short* WT     = (short*)alloc((size_t)9 * 512 * 512 * 2);
    float* qall   = (float*)alloc((size_t)384 * 2048 * 4);   // [qd|hqp|qh'|hq2']
    float* qe     = (float*)alloc((size_t)512 * 512 * 4);
    float* hqf    = (float*)alloc((size_t)256 * 512 * 4);
    float* hsp    = (float*)alloc((size_t)4 * 16384 * 4);    // hscores col-block partials
    short* tkb    = (short*)alloc((size_t)4096 * 512 * 2);
    short* tkWTb  = (short*)alloc((size_t)4096 * 512 * 2);
    short* tqb    = (short*)alloc((size_t)16384 * 512 * 2);
    short* scb    = (short*)alloc((size_t)16384 * 512 * 2);  // scores -> gh
    short* Pb     = (short*)alloc((size_t)16384 * 512 * 2);  // tail_attn (to the end)
    short* ghb = scb;   // scores dead after sm

    // WT slab: 0 Wd^T | 1 Whq1^T | 2 Wtq2^T | 3 Whq2^T | 4 We^T | 5 Wtk^T
    //          6 Wtout1^T | 7 Wtout2^T | 8 Whk^T
    WTDesc wd;
    wd.src[0] = W_tq;               wd.dst[0] = WT;
    wd.src[1] = W_hq;               wd.dst[1] = WT + (size_t)1 * 262144;
    wd.src[2] = W_tq + 512 * 512;   wd.dst[2] = WT + (size_t)2 * 262144;
    wd.src[3] = W_hq + 512 * 512;   wd.dst[3] = WT + (size_t)3 * 262144;
    wd.src[4] = W_tq + 1024 * 512;  wd.dst[4] = WT + (size_t)4 * 262144;
    wd.src[5] = W_tk;               wd.dst[5] = WT + (size_t)5 * 262144;
    wd.src[6] = W_tout;             wd.dst[6] = WT + (size_t)6 * 262144;
    wd.src[7] = W_tout + 512 * 512; wd.dst[7] = WT + (size_t)7 * 262144;
    wd.src[8] = W_hk;               wd.dst[8] = WT + (size_t)8 * 262144;

    // 1: casts / gathers / weight transposes
    prep<<<7440, 256, 0, stream>>>(dec_out, history, decb, emb, head, tail, embAll, wd);
    // 2: qall | qe | tk
    mgemm_multi<<<192, 256, 0, stream>>>(decb, WT, qall, embAll, WT + (size_t)4 * 262144, qe,
                                         WT + (size_t)5 * 262144, b_tk, tkb);
    // 3: build tq | tkWT = Wtout1^T @ tk^T (per b) | build hq
    l3_kernel<<<8448, 256, 0, stream>>>(qall, qe, b_tq, tqb, WT + (size_t)6 * 262144, tkb, tkWTb,
                                        b_hq, hqf);
    // 4: raw scores = tq @ tk^T (per b), bf16
    mgemm<0, 1, 0><<<dim3(4, 16, 8), 256, 0, stream>>>(
        tqb, (long)2048 * 512, tkb, 262144, nullptr, 0, nullptr, nullptr,
        scb, (long)2048 * 512, 512, 512);
    // 5: mask + softmax -> P
    sm_kernel<<<4096, 256, 0, stream>>>(scb, adj, dup, Pb);
    // 6: gh = tanh(P @ tkWT^T + tq @ Wtout2^T)   (writes over scb)
    mgemm<2, 1, 1><<<dim3(4, 16, 8), 256, 0, stream>>>(
        Pb, (long)2048 * 512, tkWTb, 262144, tqb, (long)2048 * 512, WT + (size_t)7 * 262144,
        nullptr, ghb, (long)2048 * 512, 512, 512);
    // 7: hscores partials = elu(gh @ Whk^T + b_hk) . hq   (no hk materialization)
    mgemm_hs<<<dim3(4, 128), 256, 0, stream>>>(ghb, WT + (size_t)8 * 262144, b_hk, hqf, hsp);
    // 8: head softmax + prob + log
    fused_head<<<256, 256, 0, stream>>>(hsp, head, Pb, out);
}